// Round 1
// baseline (324.179 us; speedup 1.0000x reference)
//
#include <hip/hip_runtime.h>
#include <hip/hip_fp16.h>

#define NPOS 26688

struct PairInfo {
  int iq, v, Hs, gH, gW, base;
  float tx1, tx2, ty1, ty2;
  float sx1, sx2, sy1, sy2;
};

__constant__ PairInfo g_pairs[6] = {
  {0,1,32,25,24,    0, -0.80f,0.70f,-0.500f,-0.475f,  -0.90f,0.60f,-0.60f,0.60f},
  {0,2,12,25,24, 4800, -0.75f,0.75f, 0.100f, 0.125f,  -0.80f,0.80f,-0.80f,0.80f},
  {0,3,12,22,24, 9600, -0.60f,0.90f,-0.200f,-0.178f,  -0.70f,0.90f,-0.90f,0.70f},
  {1,0,32,22,24,13824, -0.70f,0.80f, 0.300f, 0.322f,  -0.85f,0.65f,-0.50f,0.90f},
  {1,2,12,24,22,18048, -0.90f,0.50f,-0.100f,-0.076f,  -0.60f,0.95f,-0.95f,0.60f},
  {1,3,12,24,23,22272, -0.50f,0.95f, 0.200f, 0.224f,  -0.90f,0.90f,-0.40f,0.95f},
};

// ---------------- prep: temp from epoch ----------------
__global__ __launch_bounds__(64) void dino_prep(const int* __restrict__ epoch_p,
                                                float* __restrict__ temps) {
  if (threadIdx.x == 0) {
    int e = epoch_p[0];
    if (e < 0) e = 0;
    if (e > 99) e = 99;
    double temp = (e < 30) ? (0.04 + (double)e * ((0.07 - 0.04) / 29.0)) : 0.07;
    float tf = (float)temp;
    temps[0] = tf;
    temps[1] = 1.0f / tf;
  }
}

// ---------------- teacher softmax stats (max, 1/sumexp) per (view,b,y,x) ----------------
__global__ __launch_bounds__(256) void dino_stats(const float* __restrict__ tg0,
                                                  const float* __restrict__ tg1,
                                                  const float* __restrict__ cen,
                                                  const float* __restrict__ temps,
                                                  float* __restrict__ wm,
                                                  float* __restrict__ wz) {
  int bid = blockIdx.x;                 // 512 = 2 views * 8 b * 32 y
  int y = bid & 31;
  int b = (bid >> 5) & 7;
  int view = bid >> 8;
  const float* src = view ? tg1 : tg0;

  __shared__ float cenl[2048];
  __shared__ float pm[8][32], ps[8][32];
  int t = threadIdx.x;
#pragma unroll
  for (int k = 0; k < 8; ++k) cenl[t + 256 * k] = cen[t + 256 * k];
  __syncthreads();

  int x = t & 31, cg = t >> 5;          // cg in [0,8): 256 channels each
  float invtemp = temps[1];
  const float* sp = src + (((size_t)(b * 2048 + cg * 256)) * 32 + y) * 32 + x;
  float m = -1e30f, s = 0.f;
  for (int k = 0; k < 256; ++k) {
    float v = sp[(size_t)k * 1024];
    float lg = (v - cenl[cg * 256 + k]) * invtemp;
    if (lg > m) { s = s * __expf(m - lg) + 1.f; m = lg; }
    else s += __expf(lg - m);
  }
  pm[cg][x] = m; ps[cg][x] = s;
  __syncthreads();
  if (t < 32) {
    float M = pm[0][t], S = ps[0][t];
#pragma unroll
    for (int g = 1; g < 8; ++g) {
      float m2 = pm[g][t], s2 = ps[g][t];
      if (m2 > M) { S = S * __expf(M - m2) + s2; M = m2; }
      else S += s2 * __expf(m2 - M);
    }
    int o = ((view * 8 + b) * 32 + y) * 32 + t;
    wm[o] = M;
    wz[o] = 1.f / S;
  }
}

// ---------------- 32x32 transpose (B,C,32,32)f32 -> (B,32,32,C)f16 with scale ----------------
__global__ __launch_bounds__(256) void transpose32_scale(const float* __restrict__ src,
                                                         __half* __restrict__ dst,
                                                         float scale) {
  int bid = blockIdx.x;                 // 8192 = 8 b * 32 y * 32 ctile
  int ct = bid & 31;
  int y = (bid >> 5) & 31;
  int b = bid >> 10;
  __shared__ float tile[64][33];
  int t = threadIdx.x;
  int x = t & 31, cg = t >> 5;
  const float* sp = src + (((size_t)(b * 2048 + ct * 64)) * 32 + y) * 32 + x;
#pragma unroll
  for (int k = 0; k < 8; ++k) tile[cg * 8 + k][x] = sp[(size_t)(cg * 8 + k) * 1024];
  __syncthreads();
  __half* dp = dst + ((size_t)(b * 32 + y) * 32) * 2048 + ct * 64;
#pragma unroll
  for (int k = 0; k < 8; ++k) {
    int idx = t + 256 * k;
    int cc = idx & 63, xx = idx >> 6;
    dp[(size_t)xx * 2048 + cc] = __float2half(tile[cc][xx] * scale);
  }
}

// ---------------- teacher: transpose + softmax-prob (B,C,32,32)f32 -> (B,32,32,C)f16 ----------------
__global__ __launch_bounds__(256) void teacher_prob32(const float* __restrict__ src,
                                                      __half* __restrict__ dst,
                                                      const float* __restrict__ cen,
                                                      const float* __restrict__ wmv,
                                                      const float* __restrict__ wzv,
                                                      const float* __restrict__ temps) {
  int bid = blockIdx.x;
  int ct = bid & 31;
  int y = (bid >> 5) & 31;
  int b = bid >> 10;
  __shared__ float tile[64][33];
  __shared__ float sm[32], sz[32];
  int t = threadIdx.x;
  float invtemp = temps[1];
  if (t < 32) {
    sm[t] = wmv[(b * 32 + y) * 32 + t];
    sz[t] = wzv[(b * 32 + y) * 32 + t];
  }
  int x = t & 31, cg = t >> 5;
  const float* sp = src + (((size_t)(b * 2048 + ct * 64)) * 32 + y) * 32 + x;
#pragma unroll
  for (int k = 0; k < 8; ++k) tile[cg * 8 + k][x] = sp[(size_t)(cg * 8 + k) * 1024];
  __syncthreads();
  __half* dp = dst + ((size_t)(b * 32 + y) * 32) * 2048 + ct * 64;
#pragma unroll
  for (int k = 0; k < 8; ++k) {
    int idx = t + 256 * k;
    int cc = idx & 63, xx = idx >> 6;
    float v = tile[cc][xx];
    float p = __expf((v - cen[ct * 64 + cc]) * invtemp - sm[xx]) * sz[xx];
    dp[(size_t)xx * 2048 + cc] = __float2half(p);
  }
}

// ---------------- 12x12 transpose (B,C,12,12)f32 -> (B,12,12,C)f16 with scale ----------------
__global__ __launch_bounds__(256) void transpose12_scale(const float* __restrict__ src,
                                                         __half* __restrict__ dst,
                                                         float scale) {
  int idx = blockIdx.x * 256 + threadIdx.x;   // 8*144*2048 = 2359296
  int c = idx & 2047;
  int r = idx >> 11;                          // b*144 + yx
  int yx = r % 144;
  int b = r / 144;
  dst[idx] = __float2half(src[((size_t)(b * 2048 + c)) * 144 + yx] * scale);
}

// ---------------- helpers ----------------
__device__ inline void load8(const __half* p, float* o) {
  union { float4 f4; __half2 h2[4]; } u;
  u.f4 = *reinterpret_cast<const float4*>(p);
#pragma unroll
  for (int q = 0; q < 4; ++q) {
    float2 f = __half22float2(u.h2[q]);
    o[2 * q] = f.x;
    o[2 * q + 1] = f.y;
  }
}

__device__ inline void lse_merge(float& m, float& s, float m2, float s2) {
  if (m2 > m) { s = s * __expf(m - m2) + s2; m = m2; }
  else s += s2 * __expf(m2 - m);
}

struct Coords {
  int tx0, tx1, ty0, ty1, sx0, sx1, sy0, sy1, b, hs, iq, v;
  float wt00, wt01, wt10, wt11, ws00, ws01, ws10, ws11;
};

__device__ inline Coords decode_pos(int pos) {
  int p = 0;
#pragma unroll
  for (int q = 1; q < 6; ++q) p += (pos >= g_pairs[q].base) ? 1 : 0;
  PairInfo pi = g_pairs[p];
  int idx = pos - pi.base;
  int per = pi.gH * pi.gW;
  int b = idx / per;
  int r = idx - b * per;
  int i = r / pi.gW;
  int j = r - i * pi.gW;

  // NOTE: reference swaps gx/gy — image COLUMN index comes from the y-linspace (rows, i),
  // image ROW index from the x-linspace (cols, j).
  float tyy = pi.ty1 + (float)i * (pi.ty2 - pi.ty1) / (float)(pi.gH - 1);
  float txx = pi.tx1 + (float)j * (pi.tx2 - pi.tx1) / (float)(pi.gW - 1);
  float tix = fminf(fmaxf((tyy + 1.0f) * 16.0f - 0.5f, 0.0f), 31.0f);
  float tiy = fminf(fmaxf((txx + 1.0f) * 16.0f - 0.5f, 0.0f), 31.0f);
  Coords c;
  c.tx0 = (int)tix; c.ty0 = (int)tiy;
  float wxt = tix - (float)c.tx0, wyt = tiy - (float)c.ty0;
  c.tx1 = min(c.tx0 + 1, 31); c.ty1 = min(c.ty0 + 1, 31);

  int hs = pi.Hs;
  float hh = 0.5f * (float)hs, hm = (float)(hs - 1);
  float syy = pi.sy1 + (float)i * (pi.sy2 - pi.sy1) / (float)(pi.gH - 1);
  float sxx = pi.sx1 + (float)j * (pi.sx2 - pi.sx1) / (float)(pi.gW - 1);
  float six = fminf(fmaxf((syy + 1.0f) * hh - 0.5f, 0.0f), hm);
  float siy = fminf(fmaxf((sxx + 1.0f) * hh - 0.5f, 0.0f), hm);
  c.sx0 = (int)six; c.sy0 = (int)siy;
  float wxs = six - (float)c.sx0, wys = siy - (float)c.sy0;
  c.sx1 = min(c.sx0 + 1, hs - 1); c.sy1 = min(c.sy0 + 1, hs - 1);

  c.wt00 = (1.f - wyt) * (1.f - wxt); c.wt01 = (1.f - wyt) * wxt;
  c.wt10 = wyt * (1.f - wxt);         c.wt11 = wyt * wxt;
  c.ws00 = (1.f - wys) * (1.f - wxs); c.ws01 = (1.f - wys) * wxs;
  c.ws10 = wys * (1.f - wxs);         c.ws11 = wys * wxs;
  c.b = b; c.hs = hs; c.iq = pi.iq; c.v = pi.v;
  return c;
}

__device__ inline void finish_block(float m, float sum, float dot, float* losses, int pos) {
  int tid = threadIdx.x;
#pragma unroll
  for (int off = 32; off; off >>= 1) {
    float m2 = __shfl_down(m, off);
    float s2 = __shfl_down(sum, off);
    float d2 = __shfl_down(dot, off);
    dot += d2;
    lse_merge(m, sum, m2, s2);
  }
  __shared__ float rm[4], rs[4], rd[4];
  int w = tid >> 6;
  if ((tid & 63) == 0) { rm[w] = m; rs[w] = sum; rd[w] = dot; }
  __syncthreads();
  if (tid == 0) {
    m = rm[0]; sum = rs[0]; dot = rd[0];
#pragma unroll
    for (int q = 1; q < 4; ++q) { dot += rd[q]; lse_merge(m, sum, rm[q], rs[q]); }
    losses[pos] = m + logf(sum) - dot;
  }
}

// ---------------- main (transposed fp16 path): 1 block per output position ----------------
__global__ __launch_bounds__(256) void dino_main(
    const __half* __restrict__ Tp0, const __half* __restrict__ Tp1,
    const __half* __restrict__ S0, const __half* __restrict__ S1,
    const __half* __restrict__ S2, const __half* __restrict__ S3,
    float* __restrict__ losses) {
  int pos = blockIdx.x;
  Coords c = decode_pos(pos);

  const __half* T = c.iq ? Tp1 : Tp0;
  const __half* S = (c.v == 0) ? S0 : (c.v == 1) ? S1 : (c.v == 2) ? S2 : S3;

  size_t tplane = (size_t)c.b * 1024 * 2048;
  const __half* t00p = T + tplane + (size_t)(c.ty0 * 32 + c.tx0) * 2048;
  const __half* t01p = T + tplane + (size_t)(c.ty0 * 32 + c.tx1) * 2048;
  const __half* t10p = T + tplane + (size_t)(c.ty1 * 32 + c.tx0) * 2048;
  const __half* t11p = T + tplane + (size_t)(c.ty1 * 32 + c.tx1) * 2048;
  size_t splane = (size_t)c.b * c.hs * c.hs * 2048;
  const __half* s00p = S + splane + (size_t)(c.sy0 * c.hs + c.sx0) * 2048;
  const __half* s01p = S + splane + (size_t)(c.sy0 * c.hs + c.sx1) * 2048;
  const __half* s10p = S + splane + (size_t)(c.sy1 * c.hs + c.sx0) * 2048;
  const __half* s11p = S + splane + (size_t)(c.sy1 * c.hs + c.sx1) * 2048;

  int cb = threadIdx.x * 8;
  float a00[8], a01[8], a10[8], a11[8];
  float b00[8], b01[8], b10[8], b11[8];
  load8(s00p + cb, a00); load8(s01p + cb, a01);
  load8(s10p + cb, a10); load8(s11p + cb, a11);
  load8(t00p + cb, b00); load8(t01p + cb, b01);
  load8(t10p + cb, b10); load8(t11p + cb, b11);

  float m = -1e30f, sum = 0.f, dot = 0.f;
#pragma unroll
  for (int q = 0; q < 8; ++q) {
    float sc = c.ws00 * a00[q] + c.ws01 * a01[q] + c.ws10 * a10[q] + c.ws11 * a11[q];
    float tc = c.wt00 * b00[q] + c.wt01 * b01[q] + c.wt10 * b10[q] + c.wt11 * b11[q];
    dot = fmaf(tc, sc, dot);
    if (sc > m) { sum = sum * __expf(m - sc) + 1.f; m = sc; }
    else sum += __expf(sc - m);
  }
  finish_block(m, sum, dot, losses, pos);
}

// ---------------- main (fallback, strided reads from raw inputs) ----------------
__global__ __launch_bounds__(256) void dino_main_direct(
    const float* __restrict__ tg0, const float* __restrict__ tg1,
    const float* __restrict__ sg0, const float* __restrict__ sg1,
    const float* __restrict__ sl0, const float* __restrict__ sl1,
    const float* __restrict__ cen, const float* __restrict__ wm,
    const float* __restrict__ wz, const float* __restrict__ temps,
    float* __restrict__ losses) {
  int pos = blockIdx.x;
  Coords c = decode_pos(pos);
  float invtemp = temps[1];

  const float* T = c.iq ? tg1 : tg0;
  const float* S = (c.v == 0) ? sg0 : (c.v == 1) ? sg1 : (c.v == 2) ? sl0 : sl1;

  int sb = (c.iq * 8 + c.b) * 1024;
  float m00 = wm[sb + c.ty0 * 32 + c.tx0], z00 = wz[sb + c.ty0 * 32 + c.tx0];
  float m01 = wm[sb + c.ty0 * 32 + c.tx1], z01 = wz[sb + c.ty0 * 32 + c.tx1];
  float m10 = wm[sb + c.ty1 * 32 + c.tx0], z10 = wz[sb + c.ty1 * 32 + c.tx0];
  float m11 = wm[sb + c.ty1 * 32 + c.tx1], z11 = wz[sb + c.ty1 * 32 + c.tx1];

  float m = -1e30f, sum = 0.f, dot = 0.f;
  for (int k = 0; k < 8; ++k) {
    int ch = threadIdx.x + (k << 8);
    float cv = cen[ch];
    size_t tb = ((size_t)(c.b * 2048 + ch)) * 32;
    float p00 = __expf((T[(tb + c.ty0) * 32 + c.tx0] - cv) * invtemp - m00) * z00;
    float p01 = __expf((T[(tb + c.ty0) * 32 + c.tx1] - cv) * invtemp - m01) * z01;
    float p10 = __expf((T[(tb + c.ty1) * 32 + c.tx0] - cv) * invtemp - m10) * z10;
    float p11 = __expf((T[(tb + c.ty1) * 32 + c.tx1] - cv) * invtemp - m11) * z11;
    float tc = c.wt00 * p00 + c.wt01 * p01 + c.wt10 * p10 + c.wt11 * p11;

    size_t sbase = ((size_t)(c.b * 2048 + ch)) * c.hs;
    float v00 = S[(sbase + c.sy0) * c.hs + c.sx0];
    float v01 = S[(sbase + c.sy0) * c.hs + c.sx1];
    float v10 = S[(sbase + c.sy1) * c.hs + c.sx0];
    float v11 = S[(sbase + c.sy1) * c.hs + c.sx1];
    float sc = 10.f * (c.ws00 * v00 + c.ws01 * v01 + c.ws10 * v10 + c.ws11 * v11);

    dot = fmaf(tc, sc, dot);
    if (sc > m) { sum = sum * __expf(m - sc) + 1.f; m = sc; }
    else sum += __expf(sc - m);
  }
  finish_block(m, sum, dot, losses, pos);
}

// ---------------- final mean ----------------
__global__ __launch_bounds__(256) void dino_reduce(const float* __restrict__ losses,
                                                   float* __restrict__ out) {
  __shared__ double sd[256];
  int t = threadIdx.x;
  double a = 0.0;
  for (int i = t; i < NPOS; i += 256) a += (double)losses[i];
  sd[t] = a;
  __syncthreads();
  for (int off = 128; off; off >>= 1) {
    if (t < off) sd[t] += sd[t + off];
    __syncthreads();
  }
  if (t == 0) out[0] = (float)(sd[0] / (double)NPOS);
}

extern "C" void kernel_launch(void* const* d_in, const int* in_sizes, int n_in,
                              void* d_out, int out_size, void* d_ws, size_t ws_size,
                              hipStream_t stream) {
  const float* sg0 = (const float*)d_in[0];
  const float* sg1 = (const float*)d_in[1];
  const float* sl0 = (const float*)d_in[2];
  const float* sl1 = (const float*)d_in[3];
  const float* tg0 = (const float*)d_in[4];
  const float* tg1 = (const float*)d_in[5];
  const float* cen = (const float*)d_in[6];
  const int* epoch = (const int*)d_in[7];
  float* out = (float*)d_out;
  char* w = (char*)d_ws;

  // ws layout (bytes)
  const size_t OFF_TEMP = 0;
  const size_t OFF_M = 256;                       // 2*8*32*32 f32 = 64KB
  const size_t OFF_Z = OFF_M + 65536;
  const size_t OFF_LOSS = OFF_Z + 65536;          // 26688 f32
  const size_t OFF_T = 262144;
  const size_t SZ_BIG = (size_t)8 * 32 * 32 * 2048 * 2;   // 33554432
  const size_t SZ_SMALL = (size_t)8 * 12 * 12 * 2048 * 2; // 4718592
  const size_t WS_NEED = OFF_T + 4 * SZ_BIG + 2 * SZ_SMALL; // 143917056

  float* temps = (float*)(w + OFF_TEMP);
  float* wm = (float*)(w + OFF_M);
  float* wz = (float*)(w + OFF_Z);
  float* losses = (float*)(w + OFF_LOSS);

  dino_prep<<<1, 64, 0, stream>>>(epoch, temps);
  dino_stats<<<512, 256, 0, stream>>>(tg0, tg1, cen, temps, wm, wz);

  if (ws_size >= WS_NEED) {
    __half* Tp0 = (__half*)(w + OFF_T);
    __half* Tp1 = (__half*)(w + OFF_T + SZ_BIG);
    __half* Sg0 = (__half*)(w + OFF_T + 2 * SZ_BIG);
    __half* Sg1 = (__half*)(w + OFF_T + 3 * SZ_BIG);
    __half* Sl0 = (__half*)(w + OFF_T + 4 * SZ_BIG);
    __half* Sl1 = (__half*)(w + OFF_T + 4 * SZ_BIG + SZ_SMALL);

    transpose32_scale<<<8192, 256, 0, stream>>>(sg0, Sg0, 10.f);
    transpose32_scale<<<8192, 256, 0, stream>>>(sg1, Sg1, 10.f);
    transpose12_scale<<<9216, 256, 0, stream>>>(sl0, Sl0, 10.f);
    transpose12_scale<<<9216, 256, 0, stream>>>(sl1, Sl1, 10.f);
    teacher_prob32<<<8192, 256, 0, stream>>>(tg0, Tp0, cen, wm, wz, temps);
    teacher_prob32<<<8192, 256, 0, stream>>>(tg1, Tp1, cen, wm + 8192, wz + 8192, temps);
    dino_main<<<NPOS, 256, 0, stream>>>(Tp0, Tp1, Sg0, Sg1, Sl0, Sl1, losses);
  } else {
    dino_main_direct<<<NPOS, 256, 0, stream>>>(tg0, tg1, sg0, sg1, sl0, sl1,
                                               cen, wm, wz, temps, losses);
  }
  dino_reduce<<<1, 256, 0, stream>>>(losses, out);
}

// Round 2
// 248.371 us; speedup vs baseline: 1.3052x; 1.3052x over previous
//
#include <hip/hip_runtime.h>
#include <hip/hip_fp16.h>

#define NPOS 26688

struct PairInfo {
  int iq, v, Hs, gH, gW, base;
  float tx1, tx2, ty1, ty2;
  float sx1, sx2, sy1, sy2;
};

__constant__ PairInfo g_pairs[6] = {
  {0,1,32,25,24,    0, -0.80f,0.70f,-0.500f,-0.475f,  -0.90f,0.60f,-0.60f,0.60f},
  {0,2,12,25,24, 4800, -0.75f,0.75f, 0.100f, 0.125f,  -0.80f,0.80f,-0.80f,0.80f},
  {0,3,12,22,24, 9600, -0.60f,0.90f,-0.200f,-0.178f,  -0.70f,0.90f,-0.90f,0.70f},
  {1,0,32,22,24,13824, -0.70f,0.80f, 0.300f, 0.322f,  -0.85f,0.65f,-0.50f,0.90f},
  {1,2,12,24,22,18048, -0.90f,0.50f,-0.100f,-0.076f,  -0.60f,0.95f,-0.95f,0.60f},
  {1,3,12,24,23,22272, -0.50f,0.95f, 0.200f, 0.224f,  -0.90f,0.90f,-0.40f,0.95f},
};

__device__ inline float get_invtemp(const int* __restrict__ ep) {
  int e = ep[0];
  e = e < 0 ? 0 : (e > 99 ? 99 : e);
  float temp = (e < 30) ? (0.04f + (float)e * (0.03f / 29.0f)) : 0.07f;
  return 1.0f / temp;
}

__device__ inline void online_upd(float& m, float& s, float lg) {
  if (lg > m) { s = s * __expf(m - lg) + 1.f; m = lg; }
  else s += __expf(lg - m);
}

__device__ inline void lse_merge(float& m, float& s, float m2, float s2) {
  if (m2 > m) { s = s * __expf(m - m2) + s2; m = m2; }
  else s += s2 * __expf(m2 - m);
}

// ---------------- teacher softmax partial stats: 8 channel-chunks per texel-row ----------------
__global__ __launch_bounds__(256) void dino_stats_part(
    const float* __restrict__ tg0, const float* __restrict__ tg1,
    const float* __restrict__ cen, const int* __restrict__ ep,
    float* __restrict__ part_m, float* __restrict__ part_s) {
  int bid = blockIdx.x;            // 8192 = view(2) * b(8) * y(32) * chunk(8)
  int chunk = bid & 7;
  int y = (bid >> 3) & 31;
  int b = (bid >> 8) & 7;
  int view = bid >> 11;
  const float* __restrict__ src = view ? tg1 : tg0;
  float invtemp = get_invtemp(ep);

  __shared__ float cenl[256];
  int t = threadIdx.x;
  cenl[t] = cen[chunk * 256 + t];
  __syncthreads();

  int xg = t & 7;                  // x = xg*4 .. xg*4+3
  int sub = t >> 5 == 0 ? t >> 3 : t >> 3;  // sub = t>>3 in [0,32)
  sub = t >> 3;
  const float* sp = src + (((size_t)(b * 2048 + chunk * 256 + sub)) * 32 + y) * 32 + xg * 4;
  float m0 = -1e30f, m1 = -1e30f, m2 = -1e30f, m3 = -1e30f;
  float s0 = 0.f, s1 = 0.f, s2 = 0.f, s3 = 0.f;
#pragma unroll
  for (int k = 0; k < 8; ++k) {
    float4 v = *reinterpret_cast<const float4*>(sp + (size_t)k * 32768);  // +32 channels
    float cv = cenl[k * 32 + sub];
    online_upd(m0, s0, (v.x - cv) * invtemp);
    online_upd(m1, s1, (v.y - cv) * invtemp);
    online_upd(m2, s2, (v.z - cv) * invtemp);
    online_upd(m3, s3, (v.w - cv) * invtemp);
  }
  __shared__ float pm[32][33], ps[32][33];
  pm[sub][xg * 4 + 0] = m0; ps[sub][xg * 4 + 0] = s0;
  pm[sub][xg * 4 + 1] = m1; ps[sub][xg * 4 + 1] = s1;
  pm[sub][xg * 4 + 2] = m2; ps[sub][xg * 4 + 2] = s2;
  pm[sub][xg * 4 + 3] = m3; ps[sub][xg * 4 + 3] = s3;
  __syncthreads();
  if (t < 32) {
    float M = pm[0][t], S = ps[0][t];
#pragma unroll
    for (int g = 1; g < 32; ++g) lse_merge(M, S, pm[g][t], ps[g][t]);
    part_m[bid * 32 + t] = M;
    part_s[bid * 32 + t] = S;
  }
}

// ---------------- merge 8 chunk-partials -> (max, 1/sumexp) per texel ----------------
__global__ __launch_bounds__(256) void dino_merge(
    const float* __restrict__ part_m, const float* __restrict__ part_s,
    float* __restrict__ wm, float* __restrict__ wz) {
  int e = blockIdx.x * 256 + threadIdx.x;   // 16384 = view*8b*32y * 32x
  int x = e & 31;
  int vby = e >> 5;                          // ((view*8+b)*32+y)
  int base = vby * 8;
  float M = -1e30f, S = 0.f;
#pragma unroll
  for (int c = 0; c < 8; ++c)
    lse_merge(M, S, part_m[(base + c) * 32 + x], part_s[(base + c) * 32 + x]);
  wm[e] = M;
  wz[e] = 1.f / S;
}

// ---------------- student 32x32: (B,C,32,32)f32 -> (B,32,32,C)f16, x10 ----------------
__global__ __launch_bounds__(256) void student_t32(
    const float* __restrict__ sg0, const float* __restrict__ sg1,
    __half* __restrict__ d0, __half* __restrict__ d1) {
  int bid = blockIdx.x;     // 16384 = which(2) * b(8) * y(32) * ct(32)
  int ct = bid & 31;
  int y = (bid >> 5) & 31;
  int b = (bid >> 10) & 7;
  int which = bid >> 13;
  const float* __restrict__ src = which ? sg1 : sg0;
  __half* __restrict__ dst = which ? d1 : d0;

  __shared__ float tile[64][33];
  int t = threadIdx.x;
  int xg = t & 7, ch = t >> 3;   // ch in [0,32), two iterations cover 64 channels
  const float* sp = src + (((size_t)(b * 2048 + ct * 64 + ch)) * 32 + y) * 32 + xg * 4;
#pragma unroll
  for (int k = 0; k < 2; ++k) {
    float4 v = *reinterpret_cast<const float4*>(sp + (size_t)k * 32768);
    int cc = ch + k * 32;
    tile[cc][xg * 4 + 0] = v.x * 10.f;
    tile[cc][xg * 4 + 1] = v.y * 10.f;
    tile[cc][xg * 4 + 2] = v.z * 10.f;
    tile[cc][xg * 4 + 3] = v.w * 10.f;
  }
  __syncthreads();
  int xx = t >> 3, ccq = (t & 7) * 8;
  __half hv[8];
#pragma unroll
  for (int j = 0; j < 8; ++j) hv[j] = __float2half(tile[ccq + j][xx]);
  __half* dp = dst + (((size_t)(b * 32 + y) * 32 + xx)) * 2048 + ct * 64 + ccq;
  *reinterpret_cast<float4*>(dp) = *reinterpret_cast<float4*>(hv);
}

// ---------------- teacher 32x32: transpose + softmax-prob -> f16 ----------------
__global__ __launch_bounds__(256) void teacher_prob(
    const float* __restrict__ tg0, const float* __restrict__ tg1,
    __half* __restrict__ d0, __half* __restrict__ d1,
    const float* __restrict__ cen, const float* __restrict__ wm,
    const float* __restrict__ wz, const int* __restrict__ ep) {
  int bid = blockIdx.x;     // 16384 = view(2) * b(8) * y(32) * ct(32)
  int ct = bid & 31;
  int y = (bid >> 5) & 31;
  int b = (bid >> 10) & 7;
  int view = bid >> 13;
  const float* __restrict__ src = view ? tg1 : tg0;
  __half* __restrict__ dst = view ? d1 : d0;
  float invtemp = get_invtemp(ep);

  __shared__ float tile[64][33];
  __shared__ float sm[32], sz[32];
  int t = threadIdx.x;
  if (t < 32) {
    int o = ((view * 8 + b) * 32 + y) * 32 + t;
    sm[t] = wm[o];
    sz[t] = wz[o];
  }
  int xg = t & 7, ch = t >> 3;
  const float* sp = src + (((size_t)(b * 2048 + ct * 64 + ch)) * 32 + y) * 32 + xg * 4;
#pragma unroll
  for (int k = 0; k < 2; ++k) {
    float4 v = *reinterpret_cast<const float4*>(sp + (size_t)k * 32768);
    int cc = ch + k * 32;
    float cv = cen[ct * 64 + cc];
    tile[cc][xg * 4 + 0] = (v.x - cv) * invtemp;
    tile[cc][xg * 4 + 1] = (v.y - cv) * invtemp;
    tile[cc][xg * 4 + 2] = (v.z - cv) * invtemp;
    tile[cc][xg * 4 + 3] = (v.w - cv) * invtemp;
  }
  __syncthreads();
  int xx = t >> 3, ccq = (t & 7) * 8;
  float mM = sm[xx], zz = sz[xx];
  __half hv[8];
#pragma unroll
  for (int j = 0; j < 8; ++j) hv[j] = __float2half(__expf(tile[ccq + j][xx] - mM) * zz);
  __half* dp = dst + (((size_t)(b * 32 + y) * 32 + xx)) * 2048 + ct * 64 + ccq;
  *reinterpret_cast<float4*>(dp) = *reinterpret_cast<float4*>(hv);
}

// ---------------- student 12x12: (B,C,12,12)f32 -> (B,12,12,C)f16, x10 ----------------
__global__ __launch_bounds__(256) void student_t12(
    const float* __restrict__ sl0, const float* __restrict__ sl1,
    __half* __restrict__ d0, __half* __restrict__ d1) {
  int idx = blockIdx.x * 256 + threadIdx.x;   // 2 * 2359296 = 4718592
  int which = idx >= 2359296;
  int i = which ? idx - 2359296 : idx;
  const float* __restrict__ src = which ? sl1 : sl0;
  __half* __restrict__ dst = which ? d1 : d0;
  int c = i & 2047;
  int r = i >> 11;                            // b*144 + yx
  int yx = r % 144;
  int b = r / 144;
  dst[i] = __float2half(src[((size_t)(b * 2048 + c)) * 144 + yx] * 10.f);
}

// ---------------- helpers for main ----------------
__device__ inline void load8(const __half* p, float* o) {
  union { float4 f4; __half2 h2[4]; } u;
  u.f4 = *reinterpret_cast<const float4*>(p);
#pragma unroll
  for (int q = 0; q < 4; ++q) {
    float2 f = __half22float2(u.h2[q]);
    o[2 * q] = f.x;
    o[2 * q + 1] = f.y;
  }
}

struct Coords {
  int tx0, tx1, ty0, ty1, sx0, sx1, sy0, sy1, b, hs, iq, v;
  float wt00, wt01, wt10, wt11, ws00, ws01, ws10, ws11;
};

__device__ inline Coords decode_pos(int pos) {
  int p = 0;
#pragma unroll
  for (int q = 1; q < 6; ++q) p += (pos >= g_pairs[q].base) ? 1 : 0;
  PairInfo pi = g_pairs[p];
  int idx = pos - pi.base;
  int per = pi.gH * pi.gW;
  int b = idx / per;
  int r = idx - b * per;
  int i = r / pi.gW;
  int j = r - i * pi.gW;

  // reference swaps gx/gy: image COLUMN from the y-linspace (i), ROW from x-linspace (j)
  float tyy = pi.ty1 + (float)i * (pi.ty2 - pi.ty1) / (float)(pi.gH - 1);
  float txx = pi.tx1 + (float)j * (pi.tx2 - pi.tx1) / (float)(pi.gW - 1);
  float tix = fminf(fmaxf((tyy + 1.0f) * 16.0f - 0.5f, 0.0f), 31.0f);
  float tiy = fminf(fmaxf((txx + 1.0f) * 16.0f - 0.5f, 0.0f), 31.0f);
  Coords c;
  c.tx0 = (int)tix; c.ty0 = (int)tiy;
  float wxt = tix - (float)c.tx0, wyt = tiy - (float)c.ty0;
  c.tx1 = min(c.tx0 + 1, 31); c.ty1 = min(c.ty0 + 1, 31);

  int hs = pi.Hs;
  float hh = 0.5f * (float)hs, hm = (float)(hs - 1);
  float syy = pi.sy1 + (float)i * (pi.sy2 - pi.sy1) / (float)(pi.gH - 1);
  float sxx = pi.sx1 + (float)j * (pi.sx2 - pi.sx1) / (float)(pi.gW - 1);
  float six = fminf(fmaxf((syy + 1.0f) * hh - 0.5f, 0.0f), hm);
  float siy = fminf(fmaxf((sxx + 1.0f) * hh - 0.5f, 0.0f), hm);
  c.sx0 = (int)six; c.sy0 = (int)siy;
  float wxs = six - (float)c.sx0, wys = siy - (float)c.sy0;
  c.sx1 = min(c.sx0 + 1, hs - 1); c.sy1 = min(c.sy0 + 1, hs - 1);

  c.wt00 = (1.f - wyt) * (1.f - wxt); c.wt01 = (1.f - wyt) * wxt;
  c.wt10 = wyt * (1.f - wxt);         c.wt11 = wyt * wxt;
  c.ws00 = (1.f - wys) * (1.f - wxs); c.ws01 = (1.f - wys) * wxs;
  c.ws10 = wys * (1.f - wxs);         c.ws11 = wys * wxs;
  c.b = b; c.hs = hs; c.iq = pi.iq; c.v = pi.v;
  return c;
}

__device__ inline void finish_block(float m, float sum, float dot, float* losses, int pos) {
  int tid = threadIdx.x;
#pragma unroll
  for (int off = 32; off; off >>= 1) {
    float m2 = __shfl_down(m, off);
    float s2 = __shfl_down(sum, off);
    float d2 = __shfl_down(dot, off);
    dot += d2;
    lse_merge(m, sum, m2, s2);
  }
  __shared__ float rm[4], rs[4], rd[4];
  int w = tid >> 6;
  if ((tid & 63) == 0) { rm[w] = m; rs[w] = sum; rd[w] = dot; }
  __syncthreads();
  if (tid == 0) {
    m = rm[0]; sum = rs[0]; dot = rd[0];
#pragma unroll
    for (int q = 1; q < 4; ++q) { dot += rd[q]; lse_merge(m, sum, rm[q], rs[q]); }
    losses[pos] = m + logf(sum) - dot;
  }
}

// ---------------- main: 1 block per output position ----------------
__global__ __launch_bounds__(256) void dino_main(
    const __half* __restrict__ Tp0, const __half* __restrict__ Tp1,
    const __half* __restrict__ S0, const __half* __restrict__ S1,
    const __half* __restrict__ S2, const __half* __restrict__ S3,
    float* __restrict__ losses) {
  int pos = blockIdx.x;
  Coords c = decode_pos(pos);

  const __half* T = c.iq ? Tp1 : Tp0;
  const __half* S = (c.v == 0) ? S0 : (c.v == 1) ? S1 : (c.v == 2) ? S2 : S3;

  size_t tplane = (size_t)c.b * 1024 * 2048;
  const __half* t00p = T + tplane + (size_t)(c.ty0 * 32 + c.tx0) * 2048;
  const __half* t01p = T + tplane + (size_t)(c.ty0 * 32 + c.tx1) * 2048;
  const __half* t10p = T + tplane + (size_t)(c.ty1 * 32 + c.tx0) * 2048;
  const __half* t11p = T + tplane + (size_t)(c.ty1 * 32 + c.tx1) * 2048;
  size_t splane = (size_t)c.b * c.hs * c.hs * 2048;
  const __half* s00p = S + splane + (size_t)(c.sy0 * c.hs + c.sx0) * 2048;
  const __half* s01p = S + splane + (size_t)(c.sy0 * c.hs + c.sx1) * 2048;
  const __half* s10p = S + splane + (size_t)(c.sy1 * c.hs + c.sx0) * 2048;
  const __half* s11p = S + splane + (size_t)(c.sy1 * c.hs + c.sx1) * 2048;

  int cb = threadIdx.x * 8;
  float a00[8], a01[8], a10[8], a11[8];
  float b00[8], b01[8], b10[8], b11[8];
  load8(s00p + cb, a00); load8(s01p + cb, a01);
  load8(s10p + cb, a10); load8(s11p + cb, a11);
  load8(t00p + cb, b00); load8(t01p + cb, b01);
  load8(t10p + cb, b10); load8(t11p + cb, b11);

  float m = -1e30f, sum = 0.f, dot = 0.f;
#pragma unroll
  for (int q = 0; q < 8; ++q) {
    float sc = c.ws00 * a00[q] + c.ws01 * a01[q] + c.ws10 * a10[q] + c.ws11 * a11[q];
    float tc = c.wt00 * b00[q] + c.wt01 * b01[q] + c.wt10 * b10[q] + c.wt11 * b11[q];
    dot = fmaf(tc, sc, dot);
    if (sc > m) { sum = sum * __expf(m - sc) + 1.f; m = sc; }
    else sum += __expf(sc - m);
  }
  finish_block(m, sum, dot, losses, pos);
}

// ---------------- final mean ----------------
__global__ __launch_bounds__(256) void dino_reduce(const float* __restrict__ losses,
                                                   float* __restrict__ out) {
  __shared__ double sd[256];
  int t = threadIdx.x;
  double a = 0.0;
  for (int i = t; i < NPOS; i += 256) a += (double)losses[i];
  sd[t] = a;
  __syncthreads();
  for (int off = 128; off; off >>= 1) {
    if (t < off) sd[t] += sd[t + off];
    __syncthreads();
  }
  if (t == 0) out[0] = (float)(sd[0] / (double)NPOS);
}

extern "C" void kernel_launch(void* const* d_in, const int* in_sizes, int n_in,
                              void* d_out, int out_size, void* d_ws, size_t ws_size,
                              hipStream_t stream) {
  const float* sg0 = (const float*)d_in[0];
  const float* sg1 = (const float*)d_in[1];
  const float* sl0 = (const float*)d_in[2];
  const float* sl1 = (const float*)d_in[3];
  const float* tg0 = (const float*)d_in[4];
  const float* tg1 = (const float*)d_in[5];
  const float* cen = (const float*)d_in[6];
  const int* epoch = (const int*)d_in[7];
  float* out = (float*)d_out;
  char* w = (char*)d_ws;

  // ws layout (bytes) — identical footprint to the passing round-1 layout
  const size_t OFF_M = 0;                         // 16384 f32 = 64KB
  const size_t OFF_Z = 65536;
  const size_t OFF_LOSS = 131072;                 // 26688 f32
  const size_t OFF_T = 262144;
  const size_t SZ_BIG = (size_t)8 * 32 * 32 * 2048 * 2;   // 33554432
  const size_t SZ_SMALL = (size_t)8 * 12 * 12 * 2048 * 2; // 4718592

  float* wm = (float*)(w + OFF_M);
  float* wz = (float*)(w + OFF_Z);
  float* losses = (float*)(w + OFF_LOSS);

  __half* Tp0 = (__half*)(w + OFF_T);
  __half* Tp1 = (__half*)(w + OFF_T + SZ_BIG);
  __half* Sg0 = (__half*)(w + OFF_T + 2 * SZ_BIG);
  __half* Sg1 = (__half*)(w + OFF_T + 3 * SZ_BIG);
  __half* Sl0 = (__half*)(w + OFF_T + 4 * SZ_BIG);
  __half* Sl1 = (__half*)(w + OFF_T + 4 * SZ_BIG + SZ_SMALL);

  // partial stats live inside the (not-yet-written) Tp0 region: 2 MB needed,
  // consumed by dino_merge BEFORE teacher_prob writes Tp0. Stream order
  // guarantees this.
  float* part_m = (float*)(w + OFF_T);
  float* part_s = (float*)(w + OFF_T + (1 << 20));

  dino_stats_part<<<8192, 256, 0, stream>>>(tg0, tg1, cen, epoch, part_m, part_s);
  dino_merge<<<64, 256, 0, stream>>>(part_m, part_s, wm, wz);
  student_t32<<<16384, 256, 0, stream>>>(sg0, sg1, Sg0, Sg1);
  student_t12<<<18432, 256, 0, stream>>>(sl0, sl1, Sl0, Sl1);
  teacher_prob<<<16384, 256, 0, stream>>>(tg0, tg1, Tp0, Tp1, cen, wm, wz, epoch);
  dino_main<<<NPOS, 256, 0, stream>>>(Tp0, Tp1, Sg0, Sg1, Sl0, Sl1, losses);
  dino_reduce<<<1, 256, 0, stream>>>(losses, out);
}

// Round 3
// 165.358 us; speedup vs baseline: 1.9605x; 1.5020x over previous
//
#include <hip/hip_runtime.h>
#include <hip/hip_fp16.h>

#define NPOS 26688

struct PairInfo {
  int iq, v, Hs, gH, gW, base, per;
  unsigned magicPer, magicW;
  float tx1, tx2, ty1, ty2;
  float sx1, sx2, sy1, sy2;
};

// magic = ceil(2^32/d); valid since (magic*d - 2^32) * n_max < 2^32 for all entries
__constant__ PairInfo g_pairs[6] = {
  {0,1,32,25,24,    0,600, 7158279u,178956971u, -0.80f,0.70f,-0.500f,-0.475f,  -0.90f,0.60f,-0.60f,0.60f},
  {0,2,12,25,24, 4800,600, 7158279u,178956971u, -0.75f,0.75f, 0.100f, 0.125f,  -0.80f,0.80f,-0.80f,0.80f},
  {0,3,12,22,24, 9600,528, 8134408u,178956971u, -0.60f,0.90f,-0.200f,-0.178f,  -0.70f,0.90f,-0.90f,0.70f},
  {1,0,32,22,24,13824,528, 8134408u,178956971u, -0.70f,0.80f, 0.300f, 0.322f,  -0.85f,0.65f,-0.50f,0.90f},
  {1,2,12,24,22,18048,528, 8134408u,195225787u, -0.90f,0.50f,-0.100f,-0.076f,  -0.60f,0.95f,-0.95f,0.60f},
  {1,3,12,24,23,22272,552, 7780739u,186737709u, -0.50f,0.95f, 0.200f, 0.224f,  -0.90f,0.90f,-0.40f,0.95f},
};

__device__ inline float get_invtemp(const int* __restrict__ ep) {
  int e = ep[0];
  e = e < 0 ? 0 : (e > 99 ? 99 : e);
  float temp = (e < 30) ? (0.04f + (float)e * (0.03f / 29.0f)) : 0.07f;
  return 1.0f / temp;
}

__device__ inline void lse_merge(float& m, float& s, float m2, float s2) {
  if (m2 > m) { s = s * __expf(m - m2) + s2; m = m2; }
  else s += s2 * __expf(m2 - m);
}

typedef _Float16 hv2 __attribute__((ext_vector_type(2)));
__device__ inline float fdot2f(__half2 a, __half2 b, float c) {
#if defined(__has_builtin)
#if __has_builtin(__builtin_amdgcn_fdot2)
  return __builtin_amdgcn_fdot2(*reinterpret_cast<hv2*>(&a),
                                *reinterpret_cast<hv2*>(&b), c, false);
#else
  float2 af = __half22float2(a), bf = __half22float2(b);
  return fmaf(af.x, bf.x, fmaf(af.y, bf.y, c));
#endif
#else
  float2 af = __half22float2(a), bf = __half22float2(b);
  return fmaf(af.x, bf.x, fmaf(af.y, bf.y, c));
#endif
}

// ---------------- teacher softmax partial stats (branchless 2-pass) ----------------
__global__ __launch_bounds__(256) void dino_stats_part(
    const float* __restrict__ tg0, const float* __restrict__ tg1,
    const float* __restrict__ cen, const int* __restrict__ ep,
    float* __restrict__ part_m, float* __restrict__ part_s) {
  int bid = blockIdx.x;            // 8192 = view(2)*b(8)*y(32)*chunk(8)
  int chunk = bid & 7;
  int y = (bid >> 3) & 31;
  int b = (bid >> 8) & 7;
  int view = bid >> 11;
  const float* __restrict__ src = view ? tg1 : tg0;
  float invtemp = get_invtemp(ep);

  __shared__ float cenl[256];
  int t = threadIdx.x;
  cenl[t] = cen[chunk * 256 + t];
  __syncthreads();

  int xg = t & 7, sub = t >> 3;    // x = xg*4..xg*4+3, sub in [0,32)
  const float* sp = src + (((size_t)(b * 2048 + chunk * 256 + sub)) * 32 + y) * 32 + xg * 4;
  float4 vv[8];
#pragma unroll
  for (int k = 0; k < 8; ++k)
    vv[k] = *reinterpret_cast<const float4*>(sp + (size_t)k * 32768);
  float4 lg[8];
#pragma unroll
  for (int k = 0; k < 8; ++k) {
    float cv = cenl[k * 32 + sub];
    lg[k].x = (vv[k].x - cv) * invtemp;
    lg[k].y = (vv[k].y - cv) * invtemp;
    lg[k].z = (vv[k].z - cv) * invtemp;
    lg[k].w = (vv[k].w - cv) * invtemp;
  }
  float4 mx = lg[0];
#pragma unroll
  for (int k = 1; k < 8; ++k) {
    mx.x = fmaxf(mx.x, lg[k].x); mx.y = fmaxf(mx.y, lg[k].y);
    mx.z = fmaxf(mx.z, lg[k].z); mx.w = fmaxf(mx.w, lg[k].w);
  }
  float4 s = make_float4(0.f, 0.f, 0.f, 0.f);
#pragma unroll
  for (int k = 0; k < 8; ++k) {
    s.x += __expf(lg[k].x - mx.x); s.y += __expf(lg[k].y - mx.y);
    s.z += __expf(lg[k].z - mx.z); s.w += __expf(lg[k].w - mx.w);
  }
  __shared__ float pm[32][33], ps[32][33];
  pm[sub][xg * 4 + 0] = mx.x; ps[sub][xg * 4 + 0] = s.x;
  pm[sub][xg * 4 + 1] = mx.y; ps[sub][xg * 4 + 1] = s.y;
  pm[sub][xg * 4 + 2] = mx.z; ps[sub][xg * 4 + 2] = s.z;
  pm[sub][xg * 4 + 3] = mx.w; ps[sub][xg * 4 + 3] = s.w;
  __syncthreads();
  if (t < 32) {
    float M = pm[0][t], S = ps[0][t];
#pragma unroll
    for (int g = 1; g < 32; ++g) lse_merge(M, S, pm[g][t], ps[g][t]);
    part_m[bid * 32 + t] = M;
    part_s[bid * 32 + t] = S;
  }
}

// ---------------- fuse1: merge partials (bid<64) | student 12x12 transpose ----------------
__global__ __launch_bounds__(256) void dino_fuse1(
    const float* __restrict__ part_m, const float* __restrict__ part_s,
    float* __restrict__ wm, float* __restrict__ wz,
    const float* __restrict__ sl0, const float* __restrict__ sl1,
    __half* __restrict__ Sl0, __half* __restrict__ Sl1) {
  __shared__ float tile[64 * 145];   // stride 145 words: odd*16 -> conflict-free
  int bid = blockIdx.x;
  int t = threadIdx.x;
  if (bid < 64) {                    // ---- merge: 16384 texels
    int e = bid * 256 + t;
    int x = e & 31;
    int base = (e >> 5) * 8;
    float M = -1e30f, S = 0.f;
#pragma unroll
    for (int c = 0; c < 8; ++c)
      lse_merge(M, S, part_m[(base + c) * 32 + x], part_s[(base + c) * 32 + x]);
    wm[e] = M;
    wz[e] = 1.f / S;
    return;
  }
  // ---- 12x12 transpose: 512 = v(2)*b(8)*ct(32), 64ch x 144yx per block
  int lb = bid - 64;
  int ct = lb & 31;
  int b = (lb >> 5) & 7;
  int vv = lb >> 8;
  const float* __restrict__ src = vv ? sl1 : sl0;
  __half* __restrict__ dst = vv ? Sl1 : Sl0;
  const float* sp = src + ((size_t)(b * 2048 + ct * 64)) * 144;
#pragma unroll
  for (int k = 0; k < 36; ++k) {     // 9216 contiguous floats in
    int idx = t + 256 * k;
    int c = idx / 144;
    int yx = idx - c * 144;
    tile[c * 145 + yx] = sp[idx] * 10.f;
  }
  __syncthreads();
  __half* dp = dst + ((size_t)(b * 144)) * 2048 + ct * 64;
#pragma unroll
  for (int k = 0; k < 5; ++k) {      // 1152 float4 chunks out
    int idx8 = t + 256 * k;
    if (idx8 < 1152) {
      int yx = idx8 >> 3, q8 = (idx8 & 7) * 8;
      __half hv[8];
#pragma unroll
      for (int j = 0; j < 8; ++j) hv[j] = __float2half(tile[(q8 + j) * 145 + yx]);
      *reinterpret_cast<float4*>(dp + (size_t)yx * 2048 + q8) =
          *reinterpret_cast<float4*>(hv);
    }
  }
}

// ---------------- prep32: student t32 (bid<16384) | teacher prob ----------------
__global__ __launch_bounds__(256) void dino_prep32(
    const float* __restrict__ sg0, const float* __restrict__ sg1,
    const float* __restrict__ tg0, const float* __restrict__ tg1,
    __half* __restrict__ Sg0, __half* __restrict__ Sg1,
    __half* __restrict__ Tp0, __half* __restrict__ Tp1,
    const float* __restrict__ cen, const float* __restrict__ wm,
    const float* __restrict__ wz, const int* __restrict__ ep) {
  int bid = blockIdx.x;
  int isT = bid >> 14;
  int lb = bid & 16383;
  int ct = lb & 31;
  int y = (lb >> 5) & 31;
  int b = (lb >> 10) & 7;
  int vv = lb >> 13;
  const float* __restrict__ src = isT ? (vv ? tg1 : tg0) : (vv ? sg1 : sg0);
  __half* __restrict__ dst = isT ? (vv ? Tp1 : Tp0) : (vv ? Sg1 : Sg0);

  __shared__ float tile[64][33];
  __shared__ float sm[32], szl[32];
  int t = threadIdx.x;
  float invtemp = 0.f;
  if (isT) {
    invtemp = get_invtemp(ep);
    if (t < 32) {
      int o = ((vv * 8 + b) * 32 + y) * 32 + t;
      sm[t] = wm[o];
      szl[t] = wz[o];
    }
  }
  int xg = t & 7, ch = t >> 3;
  const float* sp = src + (((size_t)(b * 2048 + ct * 64 + ch)) * 32 + y) * 32 + xg * 4;
  float4 v0 = *reinterpret_cast<const float4*>(sp);
  float4 v1 = *reinterpret_cast<const float4*>(sp + 32768);
  if (isT) {
    float cv0 = cen[ct * 64 + ch], cv1 = cen[ct * 64 + ch + 32];
    tile[ch][xg * 4 + 0] = (v0.x - cv0) * invtemp;
    tile[ch][xg * 4 + 1] = (v0.y - cv0) * invtemp;
    tile[ch][xg * 4 + 2] = (v0.z - cv0) * invtemp;
    tile[ch][xg * 4 + 3] = (v0.w - cv0) * invtemp;
    tile[ch + 32][xg * 4 + 0] = (v1.x - cv1) * invtemp;
    tile[ch + 32][xg * 4 + 1] = (v1.y - cv1) * invtemp;
    tile[ch + 32][xg * 4 + 2] = (v1.z - cv1) * invtemp;
    tile[ch + 32][xg * 4 + 3] = (v1.w - cv1) * invtemp;
  } else {
    tile[ch][xg * 4 + 0] = v0.x * 10.f;
    tile[ch][xg * 4 + 1] = v0.y * 10.f;
    tile[ch][xg * 4 + 2] = v0.z * 10.f;
    tile[ch][xg * 4 + 3] = v0.w * 10.f;
    tile[ch + 32][xg * 4 + 0] = v1.x * 10.f;
    tile[ch + 32][xg * 4 + 1] = v1.y * 10.f;
    tile[ch + 32][xg * 4 + 2] = v1.z * 10.f;
    tile[ch + 32][xg * 4 + 3] = v1.w * 10.f;
  }
  __syncthreads();
  int xx = t >> 3, ccq = (t & 7) * 8;
  __half hv[8];
  if (isT) {
    float mM = sm[xx], zz = szl[xx];
#pragma unroll
    for (int j = 0; j < 8; ++j)
      hv[j] = __float2half(__expf(tile[ccq + j][xx] - mM) * zz);
  } else {
#pragma unroll
    for (int j = 0; j < 8; ++j) hv[j] = __float2half(tile[ccq + j][xx]);
  }
  __half* dp = dst + (((size_t)(b * 32 + y) * 32 + xx)) * 2048 + ct * 64 + ccq;
  *reinterpret_cast<float4*>(dp) = *reinterpret_cast<float4*>(hv);
}

// ---------------- main: 1 wave per position, packed fp16 lerps, no-max LSE ----------------
union H8 { uint4 u; __half2 h[4]; };

__global__ __launch_bounds__(256) void dino_main(
    const __half* __restrict__ Tp0, const __half* __restrict__ Tp1,
    const __half* __restrict__ S0, const __half* __restrict__ S1,
    const __half* __restrict__ S2, const __half* __restrict__ S3,
    float* __restrict__ losses) {
  int wid = threadIdx.x >> 6, lane = threadIdx.x & 63;
  int pair = blockIdx.x / 1200;                 // constant div
  int slot = blockIdx.x - pair * 1200;
  PairInfo pi = g_pairs[pair];
  int posInPair = slot * 4 + wid;
  if (posInPair >= pi.per * 8) return;          // idle tail slots

  unsigned up = (unsigned)posInPair;
  int b = (int)__umulhi(up, pi.magicPer);
  int r = posInPair - b * pi.per;
  int i = (int)__umulhi((unsigned)r, pi.magicW);
  int j = r - i * pi.gW;

  // reference swaps gx/gy: image COLUMN from y-linspace (i), ROW from x-linspace (j)
  float tyy = pi.ty1 + (float)i * (pi.ty2 - pi.ty1) / (float)(pi.gH - 1);
  float txx = pi.tx1 + (float)j * (pi.tx2 - pi.tx1) / (float)(pi.gW - 1);
  float tix = fminf(fmaxf((tyy + 1.0f) * 16.0f - 0.5f, 0.0f), 31.0f);
  float tiy = fminf(fmaxf((txx + 1.0f) * 16.0f - 0.5f, 0.0f), 31.0f);
  int tx0 = (int)tix, ty0 = (int)tiy;
  float wxt = tix - (float)tx0, wyt = tiy - (float)ty0;
  int tx1i = min(tx0 + 1, 31), ty1i = min(ty0 + 1, 31);

  int hs = pi.Hs;
  float hh = 0.5f * (float)hs, hm = (float)(hs - 1);
  float syy = pi.sy1 + (float)i * (pi.sy2 - pi.sy1) / (float)(pi.gH - 1);
  float sxx = pi.sx1 + (float)j * (pi.sx2 - pi.sx1) / (float)(pi.gW - 1);
  float six = fminf(fmaxf((syy + 1.0f) * hh - 0.5f, 0.0f), hm);
  float siy = fminf(fmaxf((sxx + 1.0f) * hh - 0.5f, 0.0f), hm);
  int sx0 = (int)six, sy0 = (int)siy;
  float wxs = six - (float)sx0, wys = siy - (float)sy0;
  int sx1i = min(sx0 + 1, hs - 1), sy1i = min(sy0 + 1, hs - 1);

  const __half* __restrict__ T = pi.iq ? Tp1 : Tp0;
  const __half* __restrict__ S =
      (pi.v == 0) ? S0 : (pi.v == 1) ? S1 : (pi.v == 2) ? S2 : S3;

  int tb = b * 1024;
  int toff00 = (tb + ty0 * 32 + tx0) * 2048;
  int toff01 = (tb + ty0 * 32 + tx1i) * 2048;
  int toff10 = (tb + ty1i * 32 + tx0) * 2048;
  int toff11 = (tb + ty1i * 32 + tx1i) * 2048;
  int sb = b * hs * hs;
  int soff00 = (sb + sy0 * hs + sx0) * 2048;
  int soff01 = (sb + sy0 * hs + sx1i) * 2048;
  int soff10 = (sb + sy1i * hs + sx0) * 2048;
  int soff11 = (sb + sy1i * hs + sx1i) * 2048;

  __half2 wt00 = __float2half2_rn((1.f - wyt) * (1.f - wxt));
  __half2 wt01 = __float2half2_rn((1.f - wyt) * wxt);
  __half2 wt10 = __float2half2_rn(wyt * (1.f - wxt));
  __half2 wt11 = __float2half2_rn(wyt * wxt);
  __half2 ws00 = __float2half2_rn((1.f - wys) * (1.f - wxs));
  __half2 ws01 = __float2half2_rn((1.f - wys) * wxs);
  __half2 ws10 = __float2half2_rn(wys * (1.f - wxs));
  __half2 ws11 = __float2half2_rn(wys * wxs);

  float sum = 0.f, dot = 0.f;
#pragma unroll
  for (int k = 0; k < 4; ++k) {
    int c0 = (k << 9) + (lane << 3);            // 1KB coalesced per wave-load
    H8 t00, t01, t10, t11, a00, a01, a10, a11;
    t00.u = *reinterpret_cast<const uint4*>(T + toff00 + c0);
    t01.u = *reinterpret_cast<const uint4*>(T + toff01 + c0);
    t10.u = *reinterpret_cast<const uint4*>(T + toff10 + c0);
    t11.u = *reinterpret_cast<const uint4*>(T + toff11 + c0);
    a00.u = *reinterpret_cast<const uint4*>(S + soff00 + c0);
    a01.u = *reinterpret_cast<const uint4*>(S + soff01 + c0);
    a10.u = *reinterpret_cast<const uint4*>(S + soff10 + c0);
    a11.u = *reinterpret_cast<const uint4*>(S + soff11 + c0);
#pragma unroll
    for (int p = 0; p < 4; ++p) {
      __half2 tc2 = __hmul2(wt00, t00.h[p]);
      tc2 = __hfma2(wt01, t01.h[p], tc2);
      tc2 = __hfma2(wt10, t10.h[p], tc2);
      tc2 = __hfma2(wt11, t11.h[p], tc2);
      __half2 sc2 = __hmul2(ws00, a00.h[p]);
      sc2 = __hfma2(ws01, a01.h[p], sc2);
      sc2 = __hfma2(ws10, a10.h[p], sc2);
      sc2 = __hfma2(ws11, a11.h[p], sc2);
      dot = fdot2f(tc2, sc2, dot);
      float2 scf = __half22float2(sc2);
      sum += __expf(scf.x);
      sum += __expf(scf.y);
    }
  }
#pragma unroll
  for (int off = 32; off; off >>= 1) {
    sum += __shfl_down(sum, off);
    dot += __shfl_down(dot, off);
  }
  if (lane == 0) losses[pi.base + posInPair] = logf(sum) - dot;
}

// ---------------- final mean ----------------
__global__ __launch_bounds__(1024) void dino_reduce(const float* __restrict__ losses,
                                                    float* __restrict__ out) {
  __shared__ double sd[1024];
  int t = threadIdx.x;
  double a = 0.0;
  for (int i4 = t; i4 < 6672; i4 += 1024) {       // 26688 = 6672*4
    float4 v = *reinterpret_cast<const float4*>(losses + i4 * 4);
    a += (double)v.x + (double)v.y + (double)v.z + (double)v.w;
  }
  sd[t] = a;
  __syncthreads();
  for (int off = 512; off; off >>= 1) {
    if (t < off) sd[t] += sd[t + off];
    __syncthreads();
  }
  if (t == 0) out[0] = (float)(sd[0] / (double)NPOS);
}

extern "C" void kernel_launch(void* const* d_in, const int* in_sizes, int n_in,
                              void* d_out, int out_size, void* d_ws, size_t ws_size,
                              hipStream_t stream) {
  const float* sg0 = (const float*)d_in[0];
  const float* sg1 = (const float*)d_in[1];
  const float* sl0 = (const float*)d_in[2];
  const float* sl1 = (const float*)d_in[3];
  const float* tg0 = (const float*)d_in[4];
  const float* tg1 = (const float*)d_in[5];
  const float* cen = (const float*)d_in[6];
  const int* epoch = (const int*)d_in[7];
  float* out = (float*)d_out;
  char* w = (char*)d_ws;

  // ws layout (bytes) — identical footprint to the passing round-1/2 layout
  const size_t OFF_M = 0;                         // 16384 f32 = 64KB
  const size_t OFF_Z = 65536;
  const size_t OFF_LOSS = 131072;                 // 26688 f32
  const size_t OFF_T = 262144;
  const size_t SZ_BIG = (size_t)8 * 32 * 32 * 2048 * 2;   // 33554432
  const size_t SZ_SMALL = (size_t)8 * 12 * 12 * 2048 * 2; // 4718592

  float* wm = (float*)(w + OFF_M);
  float* wz = (float*)(w + OFF_Z);
  float* losses = (float*)(w + OFF_LOSS);

  __half* Tp0 = (__half*)(w + OFF_T);
  __half* Tp1 = (__half*)(w + OFF_T + SZ_BIG);
  __half* Sg0 = (__half*)(w + OFF_T + 2 * SZ_BIG);
  __half* Sg1 = (__half*)(w + OFF_T + 3 * SZ_BIG);
  __half* Sl0 = (__half*)(w + OFF_T + 4 * SZ_BIG);
  __half* Sl1 = (__half*)(w + OFF_T + 4 * SZ_BIG + SZ_SMALL);

  // partial stats live inside the not-yet-written Tp0 region (2 MB), consumed
  // by dino_fuse1's merge before dino_prep32 writes Tp0 (stream-ordered).
  float* part_m = (float*)(w + OFF_T);
  float* part_s = (float*)(w + OFF_T + (1 << 20));

  dino_stats_part<<<8192, 256, 0, stream>>>(tg0, tg1, cen, epoch, part_m, part_s);
  dino_fuse1<<<576, 256, 0, stream>>>(part_m, part_s, wm, wz, sl0, sl1, Sl0, Sl1);
  dino_prep32<<<32768, 256, 0, stream>>>(sg0, sg1, tg0, tg1, Sg0, Sg1, Tp0, Tp1,
                                         cen, wm, wz, epoch);
  dino_main<<<7200, 256, 0, stream>>>(Tp0, Tp1, Sg0, Sg1, Sl0, Sl1, losses);
  dino_reduce<<<1, 1024, 0, stream>>>(losses, out);
}

// Round 5
// 134.642 us; speedup vs baseline: 2.4077x; 1.2281x over previous
//
#include <hip/hip_runtime.h>
#include <hip/hip_fp16.h>

#define NPOS 26688

struct PairInfo {
  int iq, v, Hs, gH, gW, base, per;
  unsigned magicPer, magicW;
  int tOfs, tN, tCb;     // teacher compact: texel offset, #cols, col base
  int sN, sCb;           // student compact: #cols, col base (locals: 12,0)
  float tx1, tx2, ty1, ty2;
  float sx1, sx2, sy1, sy2;
};

// magic = ceil(2^32/d); error-term checked for all used ranges
__constant__ PairInfo g_pairs[6] = {
  {0,1,32,25,24,    0,600, 7158279u,178956971u,    0,2, 7, 22,5, -0.80f,0.70f,-0.500f,-0.475f,  -0.90f,0.60f,-0.60f,0.60f},
  {0,2,12,25,24, 4800,600, 7158279u,178956971u,  512,2,17, 12,0, -0.75f,0.75f, 0.100f, 0.125f,  -0.80f,0.80f,-0.80f,0.80f},
  {0,3,12,22,24, 9600,528, 8134408u,178956971u, 1024,2,12, 12,0, -0.60f,0.90f,-0.200f,-0.178f,  -0.70f,0.90f,-0.90f,0.70f},
  {1,0,32,22,24,13824,528, 8134408u,178956971u, 1536,2,20, 24,7, -0.70f,0.80f, 0.300f, 0.322f,  -0.85f,0.65f,-0.50f,0.90f},
  {1,2,12,24,22,18048,528, 8134408u,195225787u, 2048,3,13, 12,0, -0.90f,0.50f,-0.100f,-0.076f,  -0.60f,0.95f,-0.95f,0.60f},
  {1,3,12,24,23,22272,552, 7780739u,186737709u, 2816,3,18, 12,0, -0.50f,0.95f, 0.200f, 0.224f,  -0.90f,0.90f,-0.40f,0.95f},
};

// compact-teacher write tables (plain ints; x=-100 pads never match)
__constant__ int g_tentX[2][8] = {
  { 7, 8,12,13,17,18,-100,-100},
  {13,14,15,18,19,20,  20,  21},
};
__constant__ int g_tentO[2][8] = {
  {   0,   0,1024,1024, 512, 512,   0,   0},
  {2048,2048,2048,2816,2816,2816,1536,1536},
};
__constant__ int g_tentN[2][8] = {
  {2,2,2,2,2,2,2,2},
  {3,3,3,3,3,3,2,2},
};
__constant__ int g_tentC[2][8] = {
  {0,1,0,1,0,1,0,0},
  {0,1,2,0,1,2,0,1},
};
// probs-kernel texel decode tables
__constant__ int g_cumTex[6] = {0, 512, 1024, 1536, 2048, 2816};
__constant__ int g_tN[6]    = {2, 2, 2, 2, 3, 3};
__constant__ int g_tCb[6]   = {7, 17, 12, 20, 13, 18};

__device__ inline float get_invtemp(const int* __restrict__ ep) {
  int e = ep[0];
  e = e < 0 ? 0 : (e > 99 ? 99 : e);
  float temp = (e < 30) ? (0.04f + (float)e * (0.03f / 29.0f)) : 0.07f;
  return 1.0f / temp;
}

__device__ inline void lse_merge(float& m, float& s, float m2, float s2) {
  if (m2 > m) { s = s * __expf(m - m2) + s2; m = m2; }
  else s += s2 * __expf(m2 - m);
}

__device__ inline float sel4(const float4& v, int q) {
  return q == 0 ? v.x : q == 1 ? v.y : q == 2 ? v.z : v.w;
}

typedef _Float16 hv2 __attribute__((ext_vector_type(2)));
__device__ inline float fdot2f(__half2 a, __half2 b, float c) {
#if defined(__has_builtin)
#if __has_builtin(__builtin_amdgcn_fdot2)
  return __builtin_amdgcn_fdot2(*reinterpret_cast<hv2*>(&a),
                                *reinterpret_cast<hv2*>(&b), c, false);
#else
  float2 af = __half22float2(a), bf = __half22float2(b);
  return fmaf(af.x, bf.x, fmaf(af.y, bf.y, c));
#endif
#else
  float2 af = __half22float2(a), bf = __half22float2(b);
  return fmaf(af.x, bf.x, fmaf(af.y, bf.y, c));
#endif
}

// ---------------- teacher stats + compact dLogit write ----------------
__global__ __launch_bounds__(256) void dino_stats(
    const float* __restrict__ tg0, const float* __restrict__ tg1,
    const float* __restrict__ cen, const int* __restrict__ ep,
    float* __restrict__ part_m, float* __restrict__ part_s,
    __half* __restrict__ Tc) {
  int bid = blockIdx.x;            // 8192 = view(2)*b(8)*y(32)*chunk(8)
  int chunk = bid & 7;
  int y = (bid >> 3) & 31;
  int b = (bid >> 8) & 7;
  int view = bid >> 11;
  const float* __restrict__ src = view ? tg1 : tg0;
  float invtemp = get_invtemp(ep);

  __shared__ float cenl[256];
  __shared__ float pm[32][33], ps[32][33];
  __shared__ float cm[32];
  int t = threadIdx.x;
  cenl[t] = cen[chunk * 256 + t];
  __syncthreads();

  int xg = t & 7, sub = t >> 3;    // x = xg*4..xg*4+3, sub in [0,32)
  const float* sp = src + (((size_t)(b * 2048 + chunk * 256 + sub)) * 32 + y) * 32 + xg * 4;
  float4 lg[8];
#pragma unroll
  for (int k = 0; k < 8; ++k) {
    float4 v = *reinterpret_cast<const float4*>(sp + (size_t)k * 32768);
    float cv = cenl[k * 32 + sub];
    lg[k].x = (v.x - cv) * invtemp;
    lg[k].y = (v.y - cv) * invtemp;
    lg[k].z = (v.z - cv) * invtemp;
    lg[k].w = (v.w - cv) * invtemp;
  }
  float4 mx = lg[0];
#pragma unroll
  for (int k = 1; k < 8; ++k) {
    mx.x = fmaxf(mx.x, lg[k].x); mx.y = fmaxf(mx.y, lg[k].y);
    mx.z = fmaxf(mx.z, lg[k].z); mx.w = fmaxf(mx.w, lg[k].w);
  }
  float4 s = make_float4(0.f, 0.f, 0.f, 0.f);
#pragma unroll
  for (int k = 0; k < 8; ++k) {
    s.x += __expf(lg[k].x - mx.x); s.y += __expf(lg[k].y - mx.y);
    s.z += __expf(lg[k].z - mx.z); s.w += __expf(lg[k].w - mx.w);
  }
  pm[sub][xg * 4 + 0] = mx.x; ps[sub][xg * 4 + 0] = s.x;
  pm[sub][xg * 4 + 1] = mx.y; ps[sub][xg * 4 + 1] = s.y;
  pm[sub][xg * 4 + 2] = mx.z; ps[sub][xg * 4 + 2] = s.z;
  pm[sub][xg * 4 + 3] = mx.w; ps[sub][xg * 4 + 3] = s.w;
  __syncthreads();
  if (t < 32) {
    float M = pm[0][t], S = ps[0][t];
#pragma unroll
    for (int g = 1; g < 32; ++g) lse_merge(M, S, pm[g][t], ps[g][t]);
    part_m[bid * 32 + t] = M;
    part_s[bid * 32 + t] = S;
    cm[t] = M;                     // chunk max, broadcast for dLogit write
  }
  __syncthreads();
  // compact teacher dLogits (fp16): only the 14 sampled column-slices
  int nent = view ? 8 : 6;
#pragma unroll
  for (int e = 0; e < 8; ++e) {
    if (e < nent) {
      int ex = g_tentX[view][e];
      if ((ex >> 2) == xg) {
        int q = ex & 3;
        float cmx = cm[ex & 31];
        int tex = g_tentO[view][e] + (b * 32 + y) * g_tentN[view][e] + g_tentC[view][e];
        tex = min(max(tex, 0), 3583);
        size_t base = (size_t)tex * 2048 + chunk * 256 + sub;
#pragma unroll
        for (int k = 0; k < 8; ++k)
          Tc[base + k * 32] = __float2half(sel4(lg[k], q) - cmx);
      }
    }
  }
}

// ---------------- fuse1: merge partials (bid<64) | student 12x12 transpose ----------------
__global__ __launch_bounds__(256) void dino_fuse1(
    const float* __restrict__ part_m, const float* __restrict__ part_s,
    float* __restrict__ wm, float* __restrict__ wz,
    const float* __restrict__ sl0, const float* __restrict__ sl1,
    __half* __restrict__ Sl0, __half* __restrict__ Sl1) {
  __shared__ float tile[64 * 145];
  int bid = blockIdx.x;
  int t = threadIdx.x;
  if (bid < 64) {                    // merge: 16384 texels
    int e = bid * 256 + t;
    int x = e & 31;
    int base = (e >> 5) * 8;
    float M = -1e30f, S = 0.f;
#pragma unroll
    for (int c = 0; c < 8; ++c)
      lse_merge(M, S, part_m[(base + c) * 32 + x], part_s[(base + c) * 32 + x]);
    wm[e] = M;
    wz[e] = 1.f / S;
    return;
  }
  int lb = bid - 64;                 // 512 = v(2)*b(8)*ct(32)
  int ct = lb & 31;
  int b = (lb >> 5) & 7;
  int vv = lb >> 8;
  const float* __restrict__ src = vv ? sl1 : sl0;
  __half* __restrict__ dst = vv ? Sl1 : Sl0;
  const float* sp = src + ((size_t)(b * 2048 + ct * 64)) * 144;
#pragma unroll
  for (int k = 0; k < 36; ++k) {
    int idx = t + 256 * k;
    int c = idx / 144;
    int yx = idx - c * 144;
    tile[c * 145 + yx] = sp[idx] * 10.f;
  }
  __syncthreads();
  __half* dp = dst + ((size_t)(b * 144)) * 2048 + ct * 64;
#pragma unroll
  for (int k = 0; k < 5; ++k) {
    int idx8 = t + 256 * k;
    if (idx8 < 1152) {
      int yx = idx8 >> 3, q8 = (idx8 & 7) * 8;
      __half hv[8];
#pragma unroll
      for (int j = 0; j < 8; ++j) hv[j] = __float2half(tile[(q8 + j) * 145 + yx]);
      *reinterpret_cast<float4*>(dp + (size_t)yx * 2048 + q8) =
          *reinterpret_cast<float4*>(hv);
    }
  }
}

// ---------------- fuse2: teacher probs Tc->Tp (bid<3584) | student-g windowed transpose ----------------
union H8 { uint4 u; __half2 h[4]; };

__global__ __launch_bounds__(256) void dino_fuse2(
    const __half* __restrict__ Tc, __half* __restrict__ Tp,
    const float* __restrict__ part_m, const float* __restrict__ wm,
    const float* __restrict__ wz,
    const float* __restrict__ sg0, const float* __restrict__ sg1,
    __half* __restrict__ Sg0, __half* __restrict__ Sg1) {
  __shared__ float tile[64][33];
  __shared__ float mk[10];
  int bid = blockIdx.x;
  int t = threadIdx.x;
  if (bid < 3584) {                  // ---- probs: one texel per block
    int p = 0;
#pragma unroll
    for (int q = 1; q < 6; ++q) p += (bid >= g_cumTex[q]) ? 1 : 0;
    int r = bid - g_cumTex[p];
    int n = g_tN[p];
    int by = (n == 2) ? (r >> 1) : (r / 3);
    by = min(max(by, 0), 255);
    int ci = min(max(r - by * n, 0), n - 1);
    int x = g_tCb[p] + ci;           // <= 21 < 32
    int view = (p >= 3) ? 1 : 0;
    int b = by >> 5, y = by & 31;
    int texRow = ((view * 8 + b) * 32 + y);       // < 512
    if (t < 8) mk[t] = part_m[(texRow * 8 + t) * 32 + x];
    if (t == 8) mk[8] = wm[texRow * 32 + x];
    if (t == 9) mk[9] = wz[texRow * 32 + x];
    __syncthreads();
    int tex = min(g_cumTex[p] + by * n + ci, 3583);
    size_t base = (size_t)tex * 2048 + t * 8;
    H8 hh;
    hh.u = *reinterpret_cast<const uint4*>(Tc + base);
    float off = mk[t >> 5] - mk[8];
    float invS = mk[9];
#pragma unroll
    for (int pc = 0; pc < 4; ++pc) {
      float2 f = __half22float2(hh.h[pc]);
      f.x = __expf(f.x + off) * invS;
      f.y = __expf(f.y + off) * invS;
      hh.h[pc] = __floats2half2_rn(f.x, f.y);
    }
    *reinterpret_cast<uint4*>(Tp + base) = hh.u;
    return;
  }
  // ---- student-global windowed transpose: 13312 = which(2)*b(8)*y(26)*ct(32)
  int lb = bid - 3584;
  int ct = lb & 31;
  int t2 = lb >> 5;                  // [0,416)
  int yi = t2 % 26;
  int g = t2 / 26;                   // [0,16)
  int y = yi + 1;                    // rows 1..26 only (sampled window)
  int b = g & 7;
  int which = g >> 3;
  const float* __restrict__ src = which ? sg1 : sg0;
  __half* __restrict__ dst = which ? Sg1 : Sg0;
  int cb = which ? 5 : 7;
  int n = which ? 22 : 24;

  int xg = t & 7, ch = t >> 3;
  const float* sp = src + (((size_t)(b * 2048 + ct * 64 + ch)) * 32 + y) * 32 + xg * 4;
  float4 v0 = *reinterpret_cast<const float4*>(sp);
  float4 v1 = *reinterpret_cast<const float4*>(sp + 32768);
  tile[ch][xg * 4 + 0] = v0.x * 10.f;
  tile[ch][xg * 4 + 1] = v0.y * 10.f;
  tile[ch][xg * 4 + 2] = v0.z * 10.f;
  tile[ch][xg * 4 + 3] = v0.w * 10.f;
  tile[ch + 32][xg * 4 + 0] = v1.x * 10.f;
  tile[ch + 32][xg * 4 + 1] = v1.y * 10.f;
  tile[ch + 32][xg * 4 + 2] = v1.z * 10.f;
  tile[ch + 32][xg * 4 + 3] = v1.w * 10.f;
  __syncthreads();
  int xx = t >> 3, ccq = (t & 7) * 8;
  if (xx >= cb && xx < cb + n) {
    __half hv[8];
#pragma unroll
    for (int j = 0; j < 8; ++j) hv[j] = __float2half(tile[ccq + j][xx]);
    __half* dp = dst + ((size_t)((b * 32 + y) * n + (xx - cb))) * 2048 + ct * 64 + ccq;
    *reinterpret_cast<float4*>(dp) = *reinterpret_cast<float4*>(hv);
  }
}

// ---------------- main: 1 wave per position, compact layouts, clamped ----------------
__global__ __launch_bounds__(256) void dino_main(
    const __half* __restrict__ Tp,
    const __half* __restrict__ S0, const __half* __restrict__ S1,
    const __half* __restrict__ S2, const __half* __restrict__ S3,
    float* __restrict__ losses) {
  int wid = threadIdx.x >> 6, lane = threadIdx.x & 63;
  int pair = blockIdx.x / 1200;
  int slot = blockIdx.x - pair * 1200;
  PairInfo pi = g_pairs[pair];
  int posInPair = slot * 4 + wid;
  if (posInPair >= pi.per * 8) return;

  unsigned up = (unsigned)posInPair;
  int b = (int)__umulhi(up, pi.magicPer);
  b = min(max(b, 0), 7);
  int r = posInPair - b * pi.per;
  r = min(max(r, 0), pi.per - 1);
  int i = (int)__umulhi((unsigned)r, pi.magicW);
  i = min(max(i, 0), pi.gH - 1);
  int j = r - i * pi.gW;
  j = min(max(j, 0), pi.gW - 1);

  // reference swaps gx/gy: image COLUMN from y-linspace (i), ROW from x-linspace (j)
  float tyy = pi.ty1 + (float)i * (pi.ty2 - pi.ty1) / (float)(pi.gH - 1);
  float txx = pi.tx1 + (float)j * (pi.tx2 - pi.tx1) / (float)(pi.gW - 1);
  float tix = fminf(fmaxf((tyy + 1.0f) * 16.0f - 0.5f, 0.0f), 31.0f);
  float tiy = fminf(fmaxf((txx + 1.0f) * 16.0f - 0.5f, 0.0f), 31.0f);
  int tx0 = (int)tix, ty0 = (int)tiy;
  float wxt = tix - (float)tx0, wyt = tiy - (float)ty0;
  int tx1i = min(tx0 + 1, 31), ty1i = min(ty0 + 1, 31);

  int hs = pi.Hs;
  float hh = 0.5f * (float)hs, hm = (float)(hs - 1);
  float syy = pi.sy1 + (float)i * (pi.sy2 - pi.sy1) / (float)(pi.gH - 1);
  float sxx = pi.sx1 + (float)j * (pi.sx2 - pi.sx1) / (float)(pi.gW - 1);
  float six = fminf(fmaxf((syy + 1.0f) * hh - 0.5f, 0.0f), hm);
  float siy = fminf(fmaxf((sxx + 1.0f) * hh - 0.5f, 0.0f), hm);
  int sx0 = (int)six, sy0 = (int)siy;
  float wxs = six - (float)sx0, wys = siy - (float)sy0;
  int sx1i = min(sx0 + 1, hs - 1), sy1i = min(sy0 + 1, hs - 1);

  const __half* __restrict__ S =
      (pi.v == 0) ? S0 : (pi.v == 1) ? S1 : (pi.v == 2) ? S2 : S3;

  // teacher compact: clamp cols into [0,tN)
  int tc0 = min(max(tx0 - pi.tCb, 0), pi.tN - 1);
  int tc1 = min(max(tx1i - pi.tCb, 0), pi.tN - 1);
  int trow = pi.tOfs + (b * 32 + ty0) * pi.tN;
  int trow1 = pi.tOfs + (b * 32 + ty1i) * pi.tN;
  int toff00 = min(trow + tc0, 3583) * 2048;
  int toff01 = min(trow + tc1, 3583) * 2048;
  int toff10 = min(trow1 + tc0, 3583) * 2048;
  int toff11 = min(trow1 + tc1, 3583) * 2048;
  // student compact: clamp cols into [0,sN)
  int sc0 = min(max(sx0 - pi.sCb, 0), pi.sN - 1);
  int sc1 = min(max(sx1i - pi.sCb, 0), pi.sN - 1);
  int soff00 = ((b * hs + sy0) * pi.sN + sc0) * 2048;
  int soff01 = ((b * hs + sy0) * pi.sN + sc1) * 2048;
  int soff10 = ((b * hs + sy1i) * pi.sN + sc0) * 2048;
  int soff11 = ((b * hs + sy1i) * pi.sN + sc1) * 2048;

  __half2 wt00 = __float2half2_rn((1.f - wyt) * (1.f - wxt));
  __half2 wt01 = __float2half2_rn((1.f - wyt) * wxt);
  __half2 wt10 = __float2half2_rn(wyt * (1.f - wxt));
  __half2 wt11 = __float2half2_rn(wyt * wxt);
  __half2 ws00 = __float2half2_rn((1.f - wys) * (1.f - wxs));
  __half2 ws01 = __float2half2_rn((1.f - wys) * wxs);
  __half2 ws10 = __float2half2_rn(wys * (1.f - wxs));
  __half2 ws11 = __float2half2_rn(wys * wxs);

  float sum = 0.f, dot = 0.f;
#pragma unroll
  for (int k = 0; k < 4; ++k) {
    int c0 = (k << 9) + (lane << 3);
    H8 t00, t01, t10, t11, a00, a01, a10, a11;
    t00.u = *reinterpret_cast<const uint4*>(Tp + toff00 + c0);
    t01.u = *reinterpret_cast<const uint4*>(Tp + toff01 + c0);
    t10.u = *reinterpret_cast<const uint4*>(Tp + toff10 + c0);
    t11.u = *reinterpret_cast<const uint4*>(Tp + toff11 + c0);
    a00.u = *reinterpret_cast<const uint4*>(S + soff00 + c0);
    a01.u = *reinterpret_cast<const uint4*>(S + soff01 + c0);
    a10.u = *reinterpret_cast<const uint4*>(S + soff10 + c0);
    a11.u = *reinterpret_cast<const uint4*>(S + soff11 + c0);
#pragma unroll
    for (int p = 0; p < 4; ++p) {
      __half2 tc2 = __hmul2(wt00, t00.h[p]);
      tc2 = __hfma2(wt01, t01.h[p], tc2);
      tc2 = __hfma2(wt10, t10.h[p], tc2);
      tc2 = __hfma2(wt11, t11.h[p], tc2);
      __half2 sc2 = __hmul2(ws00, a00.h[p]);
      sc2 = __hfma2(ws01, a01.h[p], sc2);
      sc2 = __hfma2(ws10, a10.h[p], sc2);
      sc2 = __hfma2(ws11, a11.h[p], sc2);
      dot = fdot2f(tc2, sc2, dot);
      float2 scf = __half22float2(sc2);
      sum += __expf(scf.x);
      sum += __expf(scf.y);
    }
  }
#pragma unroll
  for (int off = 32; off; off >>= 1) {
    sum += __shfl_down(sum, off);
    dot += __shfl_down(dot, off);
  }
  if (lane == 0) losses[pi.base + posInPair] = logf(sum) - dot;
}

// ---------------- final mean ----------------
__global__ __launch_bounds__(1024) void dino_reduce(const float* __restrict__ losses,
                                                    float* __restrict__ out) {
  __shared__ double sd[1024];
  int t = threadIdx.x;
  double a = 0.0;
  for (int i4 = t; i4 < 6672; i4 += 1024) {
    float4 v = *reinterpret_cast<const float4*>(losses + i4 * 4);
    a += (double)v.x + (double)v.y + (double)v.z + (double)v.w;
  }
  sd[t] = a;
  __syncthreads();
  for (int off = 512; off; off >>= 1) {
    if (t < off) sd[t] += sd[t + off];
    __syncthreads();
  }
  if (t == 0) out[0] = (float)(sd[0] / (double)NPOS);
}

extern "C" void kernel_launch(void* const* d_in, const int* in_sizes, int n_in,
                              void* d_out, int out_size, void* d_ws, size_t ws_size,
                              hipStream_t stream) {
  const float* sg0 = (const float*)d_in[0];
  const float* sg1 = (const float*)d_in[1];
  const float* sl0 = (const float*)d_in[2];
  const float* sl1 = (const float*)d_in[3];
  const float* tg0 = (const float*)d_in[4];
  const float* tg1 = (const float*)d_in[5];
  const float* cen = (const float*)d_in[6];
  const int* epoch = (const int*)d_in[7];
  float* out = (float*)d_out;
  char* w = (char*)d_ws;

  // ws layout (bytes), total 89,391,104 (ws >= 143,917,056 proven in round 1)
  const size_t OFF_WM  = 0;            // 65536
  const size_t OFF_WZ  = 65536;        // 65536
  const size_t OFF_LOSS= 131072;       // 106752 (pad to 262144)
  const size_t OFF_PM  = 262144;       // 1 MB
  const size_t OFF_PS  = 1310720;      // 1 MB
  const size_t OFF_TC  = 2359296;      // 14,680,064 (3584 x 2048 fp16 dlogits)
  const size_t OFF_TP  = 17039360;     // 14,680,064 (3584 x 2048 fp16 probs)
  const size_t OFF_SG0 = 31719424;     // 25,165,824 (8*32*24*2048 fp16)
  const size_t OFF_SG1 = 56885248;     // 23,068,672 (8*32*22*2048 fp16)
  const size_t OFF_SL0 = 79953920;     // 4,718,592
  const size_t OFF_SL1 = 84672512;     // 4,718,592

  float* wm = (float*)(w + OFF_WM);
  float* wz = (float*)(w + OFF_WZ);
  float* losses = (float*)(w + OFF_LOSS);
  float* part_m = (float*)(w + OFF_PM);
  float* part_s = (float*)(w + OFF_PS);
  __half* Tc  = (__half*)(w + OFF_TC);
  __half* Tp  = (__half*)(w + OFF_TP);
  __half* Sg0 = (__half*)(w + OFF_SG0);
  __half* Sg1 = (__half*)(w + OFF_SG1);
  __half* Sl0 = (__half*)(w + OFF_SL0);
  __half* Sl1 = (__half*)(w + OFF_SL1);

  dino_stats<<<8192, 256, 0, stream>>>(tg0, tg1, cen, epoch, part_m, part_s, Tc);
  dino_fuse1<<<576, 256, 0, stream>>>(part_m, part_s, wm, wz, sl0, sl1, Sl0, Sl1);
  dino_fuse2<<<16896, 256, 0, stream>>>(Tc, Tp, part_m, wm, wz, sg0, sg1, Sg0, Sg1);
  dino_main<<<7200, 256, 0, stream>>>(Tp, Sg0, Sg1, Sl0, Sl1, losses);
  dino_reduce<<<1, 1024, 0, stream>>>(losses, out);
}

// Round 6
// 113.854 us; speedup vs baseline: 2.8473x; 1.1826x over previous
//
#include <hip/hip_runtime.h>
#include <hip/hip_fp16.h>

#define NPOS 26688

struct PairInfo {
  int iq, v, Hs, gH, gW, base, per;
  unsigned magicPer, magicW;
  int tOfs, tN, tCb;     // teacher compact: texel offset, #cols, col base
  int sN, sCb;           // student compact: #cols, col base (locals: 12,0)
  float tx1, tx2, ty1, ty2;
  float sx1, sx2, sy1, sy2;
};

// magic = ceil(2^32/d); error-term checked for all used ranges
__constant__ PairInfo g_pairs[6] = {
  {0,1,32,25,24,    0,600, 7158279u,178956971u,    0,2, 7, 22,5, -0.80f,0.70f,-0.500f,-0.475f,  -0.90f,0.60f,-0.60f,0.60f},
  {0,2,12,25,24, 4800,600, 7158279u,178956971u,  512,2,17, 12,0, -0.75f,0.75f, 0.100f, 0.125f,  -0.80f,0.80f,-0.80f,0.80f},
  {0,3,12,22,24, 9600,528, 8134408u,178956971u, 1024,2,12, 12,0, -0.60f,0.90f,-0.200f,-0.178f,  -0.70f,0.90f,-0.90f,0.70f},
  {1,0,32,22,24,13824,528, 8134408u,178956971u, 1536,2,20, 24,7, -0.70f,0.80f, 0.300f, 0.322f,  -0.85f,0.65f,-0.50f,0.90f},
  {1,2,12,24,22,18048,528, 8134408u,195225787u, 2048,3,13, 12,0, -0.90f,0.50f,-0.100f,-0.076f,  -0.60f,0.95f,-0.95f,0.60f},
  {1,3,12,24,23,22272,552, 7780739u,186737709u, 2816,3,18, 12,0, -0.50f,0.95f, 0.200f, 0.224f,  -0.90f,0.90f,-0.40f,0.95f},
};

// compact-teacher write tables; view strictly in [0,2) now (grid fixed to 4096)
__constant__ int g_tentX[2][8] = {
  { 7, 8,12,13,17,18,-100,-100},
  {13,14,15,18,19,20,  20,  21},
};
__constant__ int g_tentO[2][8] = {
  {   0,   0,1024,1024, 512, 512,   0,   0},
  {2048,2048,2048,2816,2816,2816,1536,1536},
};
__constant__ int g_tentN[2][8] = {
  {2,2,2,2,2,2,2,2},
  {3,3,3,3,3,3,2,2},
};
__constant__ int g_tentC[2][8] = {
  {0,1,0,1,0,1,0,0},
  {0,1,2,0,1,2,0,1},
};
// probs-kernel texel decode tables
__constant__ int g_cumTex[6] = {0, 512, 1024, 1536, 2048, 2816};
__constant__ int g_tN[6]    = {2, 2, 2, 2, 3, 3};
__constant__ int g_tCb[6]   = {7, 17, 12, 20, 13, 18};

__device__ inline float get_invtemp(const int* __restrict__ ep) {
  int e = ep[0];
  e = e < 0 ? 0 : (e > 99 ? 99 : e);
  float temp = (e < 30) ? (0.04f + (float)e * (0.03f / 29.0f)) : 0.07f;
  return 1.0f / temp;
}

__device__ inline float sel4(const float4& v, int q) {
  return q == 0 ? v.x : q == 1 ? v.y : q == 2 ? v.z : v.w;
}

typedef _Float16 hv2 __attribute__((ext_vector_type(2)));
__device__ inline float fdot2f(__half2 a, __half2 b, float c) {
#if defined(__has_builtin)
#if __has_builtin(__builtin_amdgcn_fdot2)
  return __builtin_amdgcn_fdot2(*reinterpret_cast<hv2*>(&a),
                                *reinterpret_cast<hv2*>(&b), c, false);
#else
  float2 af = __half22float2(a), bf = __half22float2(b);
  return fmaf(af.x, bf.x, fmaf(af.y, bf.y, c));
#endif
#else
  float2 af = __half22float2(a), bf = __half22float2(b);
  return fmaf(af.x, bf.x, fmaf(af.y, bf.y, c));
#endif
}

// =========== phase1: stats(4096) | t12(2048) | t32(13312) — fused ===========
__global__ __launch_bounds__(256) void dino_phase1(
    const float* __restrict__ tg0, const float* __restrict__ tg1,
    const float* __restrict__ cen, const int* __restrict__ ep,
    float* __restrict__ part_m, float* __restrict__ part_s,
    __half* __restrict__ Tc,
    const float* __restrict__ sl0, const float* __restrict__ sl1,
    __half* __restrict__ Sl0, __half* __restrict__ Sl1,
    const float* __restrict__ sg0, const float* __restrict__ sg1,
    __half* __restrict__ Sg0, __half* __restrict__ Sg1) {
  __shared__ float smem[2960];          // 11840 B, aliased per branch
  int bid = blockIdx.x;
  int t = threadIdx.x;

  if (bid < 4096) {
    // ---------- teacher stats + compact dLogit write ----------
    // 4096 = view(2)*b(8)*y(32)*chunk(8)
    int chunk = bid & 7;
    int y = (bid >> 3) & 31;
    int b = (bid >> 8) & 7;
    int view = bid >> 11;               // in [0,2)
    const float* __restrict__ src = view ? tg1 : tg0;
    float invtemp = get_invtemp(ep);

    float* cenl = smem;                 // 256
    float* pm   = smem + 256;           // 32*33 = 1056
    float* ps   = smem + 1312;          // 1056
    float* pm2  = smem + 2368;          // 8*33 = 264
    float* ps2  = smem + 2632;          // 264
    float* cm   = smem + 2896;          // 32

    cenl[t] = cen[chunk * 256 + t];
    __syncthreads();

    int xg = t & 7, sub = t >> 3;       // x = xg*4..xg*4+3, sub in [0,32)
    const float* sp = src + (((size_t)(b * 2048 + chunk * 256 + sub)) * 32 + y) * 32 + xg * 4;
    float4 lg[8];
#pragma unroll
    for (int k = 0; k < 8; ++k) {
      float4 v = *reinterpret_cast<const float4*>(sp + (size_t)k * 32768);
      float cv = cenl[k * 32 + sub];
      lg[k].x = (v.x - cv) * invtemp;
      lg[k].y = (v.y - cv) * invtemp;
      lg[k].z = (v.z - cv) * invtemp;
      lg[k].w = (v.w - cv) * invtemp;
    }
    float4 mx = lg[0];
#pragma unroll
    for (int k = 1; k < 8; ++k) {
      mx.x = fmaxf(mx.x, lg[k].x); mx.y = fmaxf(mx.y, lg[k].y);
      mx.z = fmaxf(mx.z, lg[k].z); mx.w = fmaxf(mx.w, lg[k].w);
    }
    float4 s = make_float4(0.f, 0.f, 0.f, 0.f);
#pragma unroll
    for (int k = 0; k < 8; ++k) {
      s.x += __expf(lg[k].x - mx.x); s.y += __expf(lg[k].y - mx.y);
      s.z += __expf(lg[k].z - mx.z); s.w += __expf(lg[k].w - mx.w);
    }
    pm[sub * 33 + xg * 4 + 0] = mx.x; ps[sub * 33 + xg * 4 + 0] = s.x;
    pm[sub * 33 + xg * 4 + 1] = mx.y; ps[sub * 33 + xg * 4 + 1] = s.y;
    pm[sub * 33 + xg * 4 + 2] = mx.z; ps[sub * 33 + xg * 4 + 2] = s.z;
    pm[sub * 33 + xg * 4 + 3] = mx.w; ps[sub * 33 + xg * 4 + 3] = s.w;
    __syncthreads();
    // tree merge level 1: 8 groups x 4 subs, all 256 threads
    {
      int x = t & 31, g = t >> 5;
      float m0 = pm[(g * 4 + 0) * 33 + x], m1 = pm[(g * 4 + 1) * 33 + x];
      float m2 = pm[(g * 4 + 2) * 33 + x], m3 = pm[(g * 4 + 3) * 33 + x];
      float M = fmaxf(fmaxf(m0, m1), fmaxf(m2, m3));
      float S = ps[(g * 4 + 0) * 33 + x] * __expf(m0 - M)
              + ps[(g * 4 + 1) * 33 + x] * __expf(m1 - M)
              + ps[(g * 4 + 2) * 33 + x] * __expf(m2 - M)
              + ps[(g * 4 + 3) * 33 + x] * __expf(m3 - M);
      pm2[g * 33 + x] = M; ps2[g * 33 + x] = S;
    }
    __syncthreads();
    if (t < 32) {
      float M = pm2[t];
#pragma unroll
      for (int g = 1; g < 8; ++g) M = fmaxf(M, pm2[g * 33 + t]);
      float S = 0.f;
#pragma unroll
      for (int g = 0; g < 8; ++g) S += ps2[g * 33 + t] * __expf(pm2[g * 33 + t] - M);
      part_m[bid * 32 + t] = M;
      part_s[bid * 32 + t] = S;
      cm[t] = M;                        // chunk max for dLogit write
    }
    __syncthreads();
    // compact teacher dLogits (fp16): only the 14 sampled column-slices
    int nent = view ? 8 : 6;
#pragma unroll
    for (int e = 0; e < 8; ++e) {
      if (e < nent) {
        int ex = g_tentX[view][e];
        if ((ex >> 2) == xg) {
          int q = ex & 3;
          float cmx = cm[ex & 31];
          int tex = g_tentO[view][e] + (b * 32 + y) * g_tentN[view][e] + g_tentC[view][e];
          tex = min(max(tex, 0), 3583);
          size_t base = (size_t)tex * 2048 + chunk * 256 + sub;
#pragma unroll
          for (int k = 0; k < 8; ++k)
            Tc[base + k * 32] = __float2half(sel4(lg[k], q) - cmx);
        }
      }
    }
    return;
  }

  if (bid < 6144) {
    // ---------- student 12x12 transpose, 16 ch/block: 2048 = v(2)*b(8)*ct(128) ----------
    float* tile = smem;                 // 16*145 = 2320
    int lb = bid - 4096;
    int ct = lb & 127;
    int g = lb >> 7;
    int b = g & 7;
    int vv = g >> 3;
    const float* __restrict__ src = vv ? sl1 : sl0;
    __half* __restrict__ dst = vv ? Sl1 : Sl0;
    const float* sp = src + ((size_t)(b * 2048 + ct * 16)) * 144;
#pragma unroll
    for (int k = 0; k < 9; ++k) {       // 2304 contiguous floats in
      int idx = t + 256 * k;
      int c = idx / 144;
      int yx = idx - c * 144;
      tile[c * 145 + yx] = sp[idx] * 10.f;
    }
    __syncthreads();
    __half* dp = dst + ((size_t)(b * 144)) * 2048 + ct * 16;
#pragma unroll
    for (int k = 0; k < 2; ++k) {       // 288 float4 chunks out
      int u = t + 256 * k;
      if (u < 288) {
        int yx = u >> 1, q8 = (u & 1) * 8;
        __half hv[8];
#pragma unroll
        for (int j = 0; j < 8; ++j) hv[j] = __float2half(tile[(q8 + j) * 145 + yx]);
        *reinterpret_cast<float4*>(dp + (size_t)yx * 2048 + q8) =
            *reinterpret_cast<float4*>(hv);
      }
    }
    return;
  }

  // ---------- student-global windowed transpose: 13312 = which(2)*b(8)*y(26)*ct(32) ----------
  float* tile = smem;                   // 64*33 = 2112
  int lb = bid - 6144;
  int ct = lb & 31;
  int t2 = lb >> 5;                     // [0,416)
  int yi = t2 % 26;
  int g = t2 / 26;                      // [0,16)
  int y = yi + 1;                       // rows 1..26 only (sampled window)
  int b = g & 7;
  int which = g >> 3;
  const float* __restrict__ src = which ? sg1 : sg0;
  __half* __restrict__ dst = which ? Sg1 : Sg0;
  int cb = which ? 5 : 7;
  int n = which ? 22 : 24;

  int xg = t & 7, ch = t >> 3;
  const float* sp = src + (((size_t)(b * 2048 + ct * 64 + ch)) * 32 + y) * 32 + xg * 4;
  float4 v0 = *reinterpret_cast<const float4*>(sp);
  float4 v1 = *reinterpret_cast<const float4*>(sp + 32768);
  tile[ch * 33 + xg * 4 + 0] = v0.x * 10.f;
  tile[ch * 33 + xg * 4 + 1] = v0.y * 10.f;
  tile[ch * 33 + xg * 4 + 2] = v0.z * 10.f;
  tile[ch * 33 + xg * 4 + 3] = v0.w * 10.f;
  tile[(ch + 32) * 33 + xg * 4 + 0] = v1.x * 10.f;
  tile[(ch + 32) * 33 + xg * 4 + 1] = v1.y * 10.f;
  tile[(ch + 32) * 33 + xg * 4 + 2] = v1.z * 10.f;
  tile[(ch + 32) * 33 + xg * 4 + 3] = v1.w * 10.f;
  __syncthreads();
  int xx = t >> 3, ccq = (t & 7) * 8;
  if (xx >= cb && xx < cb + n) {
    __half hv[8];
#pragma unroll
    for (int j = 0; j < 8; ++j) hv[j] = __float2half(tile[(ccq + j) * 33 + xx]);
    __half* dp = dst + ((size_t)((b * 32 + y) * n + (xx - cb))) * 2048 + ct * 64 + ccq;
    *reinterpret_cast<float4*>(dp) = *reinterpret_cast<float4*>(hv);
  }
}

// =========== probs: Tc dlogits -> Tp probs, self-merging partials ===========
union H8 { uint4 u; __half2 h[4]; };

__global__ __launch_bounds__(256) void dino_probs(
    const __half* __restrict__ Tc, __half* __restrict__ Tp,
    const float* __restrict__ part_m, const float* __restrict__ part_s) {
  __shared__ float pm8[8], ps8[8];
  int bid = blockIdx.x;                 // 3584 texels
  int t = threadIdx.x;
  int p = 0;
#pragma unroll
  for (int q = 1; q < 6; ++q) p += (bid >= g_cumTex[q]) ? 1 : 0;
  int r = bid - g_cumTex[p];
  int n = g_tN[p];
  int by = (n == 2) ? (r >> 1) : (r / 3);
  by = min(max(by, 0), 255);
  int ci = min(max(r - by * n, 0), n - 1);
  int x = g_tCb[p] + ci;                // <= 21 < 32
  int view = (p >= 3) ? 1 : 0;
  int b = by >> 5, y = by & 31;
  int texRow = ((view * 8 + b) * 32 + y);        // < 512
  if (t < 8) {
    pm8[t] = part_m[(texRow * 8 + t) * 32 + x];
    ps8[t] = part_s[(texRow * 8 + t) * 32 + x];
  }
  __syncthreads();
  float M = pm8[0];
#pragma unroll
  for (int c = 1; c < 8; ++c) M = fmaxf(M, pm8[c]);
  float S = 0.f;
#pragma unroll
  for (int c = 0; c < 8; ++c) S += ps8[c] * __expf(pm8[c] - M);
  float invS = 1.f / S;
  float off = pm8[t >> 5] - M;

  int tex = min(g_cumTex[p] + by * n + ci, 3583);
  size_t base = (size_t)tex * 2048 + t * 8;
  H8 hh;
  hh.u = *reinterpret_cast<const uint4*>(Tc + base);
#pragma unroll
  for (int pc = 0; pc < 4; ++pc) {
    float2 f = __half22float2(hh.h[pc]);
    f.x = __expf(f.x + off) * invS;
    f.y = __expf(f.y + off) * invS;
    hh.h[pc] = __floats2half2_rn(f.x, f.y);
  }
  *reinterpret_cast<uint4*>(Tp + base) = hh.u;
}

// =========== main: 1 wave per position, compact layouts ===========
__global__ __launch_bounds__(256) void dino_main(
    const __half* __restrict__ Tp,
    const __half* __restrict__ S0, const __half* __restrict__ S1,
    const __half* __restrict__ S2, const __half* __restrict__ S3,
    float* __restrict__ losses) {
  int wid = threadIdx.x >> 6, lane = threadIdx.x & 63;
  int pair = blockIdx.x / 1200;
  int slot = blockIdx.x - pair * 1200;
  PairInfo pi = g_pairs[pair];
  int posInPair = slot * 4 + wid;
  if (posInPair >= pi.per * 8) return;

  unsigned up = (unsigned)posInPair;
  int b = (int)__umulhi(up, pi.magicPer);
  b = min(max(b, 0), 7);
  int r = posInPair - b * pi.per;
  r = min(max(r, 0), pi.per - 1);
  int i = (int)__umulhi((unsigned)r, pi.magicW);
  i = min(max(i, 0), pi.gH - 1);
  int j = r - i * pi.gW;
  j = min(max(j, 0), pi.gW - 1);

  // reference swaps gx/gy: image COLUMN from y-linspace (i), ROW from x-linspace (j)
  float tyy = pi.ty1 + (float)i * (pi.ty2 - pi.ty1) / (float)(pi.gH - 1);
  float txx = pi.tx1 + (float)j * (pi.tx2 - pi.tx1) / (float)(pi.gW - 1);
  float tix = fminf(fmaxf((tyy + 1.0f) * 16.0f - 0.5f, 0.0f), 31.0f);
  float tiy = fminf(fmaxf((txx + 1.0f) * 16.0f - 0.5f, 0.0f), 31.0f);
  int tx0 = (int)tix, ty0 = (int)tiy;
  float wxt = tix - (float)tx0, wyt = tiy - (float)ty0;
  int tx1i = min(tx0 + 1, 31), ty1i = min(ty0 + 1, 31);

  int hs = pi.Hs;
  float hh = 0.5f * (float)hs, hm = (float)(hs - 1);
  float syy = pi.sy1 + (float)i * (pi.sy2 - pi.sy1) / (float)(pi.gH - 1);
  float sxx = pi.sx1 + (float)j * (pi.sx2 - pi.sx1) / (float)(pi.gW - 1);
  float six = fminf(fmaxf((syy + 1.0f) * hh - 0.5f, 0.0f), hm);
  float siy = fminf(fmaxf((sxx + 1.0f) * hh - 0.5f, 0.0f), hm);
  int sx0 = (int)six, sy0 = (int)siy;
  float wxs = six - (float)sx0, wys = siy - (float)sy0;
  int sx1i = min(sx0 + 1, hs - 1), sy1i = min(sy0 + 1, hs - 1);

  const __half* __restrict__ S =
      (pi.v == 0) ? S0 : (pi.v == 1) ? S1 : (pi.v == 2) ? S2 : S3;

  int tc0 = min(max(tx0 - pi.tCb, 0), pi.tN - 1);
  int tc1 = min(max(tx1i - pi.tCb, 0), pi.tN - 1);
  int trow = pi.tOfs + (b * 32 + ty0) * pi.tN;
  int trow1 = pi.tOfs + (b * 32 + ty1i) * pi.tN;
  int toff00 = min(trow + tc0, 3583) * 2048;
  int toff01 = min(trow + tc1, 3583) * 2048;
  int toff10 = min(trow1 + tc0, 3583) * 2048;
  int toff11 = min(trow1 + tc1, 3583) * 2048;
  int sc0 = min(max(sx0 - pi.sCb, 0), pi.sN - 1);
  int sc1 = min(max(sx1i - pi.sCb, 0), pi.sN - 1);
  int soff00 = ((b * hs + sy0) * pi.sN + sc0) * 2048;
  int soff01 = ((b * hs + sy0) * pi.sN + sc1) * 2048;
  int soff10 = ((b * hs + sy1i) * pi.sN + sc0) * 2048;
  int soff11 = ((b * hs + sy1i) * pi.sN + sc1) * 2048;

  __half2 wt00 = __float2half2_rn((1.f - wyt) * (1.f - wxt));
  __half2 wt01 = __float2half2_rn((1.f - wyt) * wxt);
  __half2 wt10 = __float2half2_rn(wyt * (1.f - wxt));
  __half2 wt11 = __float2half2_rn(wyt * wxt);
  __half2 ws00 = __float2half2_rn((1.f - wys) * (1.f - wxs));
  __half2 ws01 = __float2half2_rn((1.f - wys) * wxs);
  __half2 ws10 = __float2half2_rn(wys * (1.f - wxs));
  __half2 ws11 = __float2half2_rn(wys * wxs);

  float sum = 0.f, dot = 0.f;
#pragma unroll
  for (int k = 0; k < 4; ++k) {
    int c0 = (k << 9) + (lane << 3);
    H8 t00, t01, t10, t11, a00, a01, a10, a11;
    t00.u = *reinterpret_cast<const uint4*>(Tp + toff00 + c0);
    t01.u = *reinterpret_cast<const uint4*>(Tp + toff01 + c0);
    t10.u = *reinterpret_cast<const uint4*>(Tp + toff10 + c0);
    t11.u = *reinterpret_cast<const uint4*>(Tp + toff11 + c0);
    a00.u = *reinterpret_cast<const uint4*>(S + soff00 + c0);
    a01.u = *reinterpret_cast<const uint4*>(S + soff01 + c0);
    a10.u = *reinterpret_cast<const uint4*>(S + soff10 + c0);
    a11.u = *reinterpret_cast<const uint4*>(S + soff11 + c0);
#pragma unroll
    for (int p = 0; p < 4; ++p) {
      __half2 tc2 = __hmul2(wt00, t00.h[p]);
      tc2 = __hfma2(wt01, t01.h[p], tc2);
      tc2 = __hfma2(wt10, t10.h[p], tc2);
      tc2 = __hfma2(wt11, t11.h[p], tc2);
      __half2 sc2 = __hmul2(ws00, a00.h[p]);
      sc2 = __hfma2(ws01, a01.h[p], sc2);
      sc2 = __hfma2(ws10, a10.h[p], sc2);
      sc2 = __hfma2(ws11, a11.h[p], sc2);
      dot = fdot2f(tc2, sc2, dot);
      float2 scf = __half22float2(sc2);
      sum += __expf(scf.x);
      sum += __expf(scf.y);
    }
  }
#pragma unroll
  for (int off = 32; off; off >>= 1) {
    sum += __shfl_down(sum, off);
    dot += __shfl_down(dot, off);
  }
  if (lane == 0) losses[pi.base + posInPair] = logf(sum) - dot;
}

// =========== final mean ===========
__global__ __launch_bounds__(1024) void dino_reduce(const float* __restrict__ losses,
                                                    float* __restrict__ out) {
  __shared__ double sd[1024];
  int t = threadIdx.x;
  double a = 0.0;
  for (int i4 = t; i4 < 6672; i4 += 1024) {
    float4 v = *reinterpret_cast<const float4*>(losses + i4 * 4);
    a += (double)v.x + (double)v.y + (double)v.z + (double)v.w;
  }
  sd[t] = a;
  __syncthreads();
  for (int off = 512; off; off >>= 1) {
    if (t < off) sd[t] += sd[t + off];
    __syncthreads();
  }
  if (t == 0) out[0] = (float)(sd[0] / (double)NPOS);
}

extern "C" void kernel_launch(void* const* d_in, const int* in_sizes, int n_in,
                              void* d_out, int out_size, void* d_ws, size_t ws_size,
                              hipStream_t stream) {
  const float* sg0 = (const float*)d_in[0];
  const float* sg1 = (const float*)d_in[1];
  const float* sl0 = (const float*)d_in[2];
  const float* sl1 = (const float*)d_in[3];
  const float* tg0 = (const float*)d_in[4];
  const float* tg1 = (const float*)d_in[5];
  const float* cen = (const float*)d_in[6];
  const int* epoch = (const int*)d_in[7];
  float* out = (float*)d_out;
  char* w = (char*)d_ws;

  // ws layout (bytes), total ~89.4 MB (>=143.9 MB proven available in round 1)
  const size_t OFF_LOSS= 131072;       // 106752 (pad to 262144)
  const size_t OFF_PM  = 262144;       // 512 KB used (4096 rows x 32 f32)
  const size_t OFF_PS  = 1310720;      // 512 KB used
  const size_t OFF_TC  = 2359296;      // 14,680,064 (3584 x 2048 fp16 dlogits)
  const size_t OFF_TP  = 17039360;     // 14,680,064 (3584 x 2048 fp16 probs)
  const size_t OFF_SG0 = 31719424;     // 25,165,824 (8*32*24*2048 fp16)
  const size_t OFF_SG1 = 56885248;     // 23,068,672 (8*32*22*2048 fp16)
  const size_t OFF_SL0 = 79953920;     // 4,718,592
  const size_t OFF_SL1 = 84672512;     // 4,718,592

  float* losses = (float*)(w + OFF_LOSS);
  float* part_m = (float*)(w + OFF_PM);
  float* part_s = (float*)(w + OFF_PS);
  __half* Tc  = (__half*)(w + OFF_TC);
  __half* Tp  = (__half*)(w + OFF_TP);
  __half* Sg0 = (__half*)(w + OFF_SG0);
  __half* Sg1 = (__half*)(w + OFF_SG1);
  __half* Sl0 = (__half*)(w + OFF_SL0);
  __half* Sl1 = (__half*)(w + OFF_SL1);

  // phase1 grid: stats[0,4096) | t12[4096,6144) | t32[6144,19456)
  dino_phase1<<<19456, 256, 0, stream>>>(tg0, tg1, cen, epoch, part_m, part_s, Tc,
                                         sl0, sl1, Sl0, Sl1, sg0, sg1, Sg0, Sg1);
  dino_probs<<<3584, 256, 0, stream>>>(Tc, Tp, part_m, part_s);
  dino_main<<<7200, 256, 0, stream>>>(Tp, Sg0, Sg1, Sl0, Sl1, losses);
  dino_reduce<<<1, 1024, 0, stream>>>(losses, out);
}